// Round 4
// baseline (16435.796 us; speedup 1.0000x reference)
//
#include <hip/hip_runtime.h>
#include <hip/hip_bf16.h>
#include <math.h>

namespace {

constexpr int B = 256, S = 64, H = 768, L = 12, NH = 12, F = 3072, T = 11;
constexpr int BS = B * S;   // 16384 rows
constexpr int RC = 8192;    // rows per FFN chunk
constexpr int NCH = BS / RC;

typedef __attribute__((ext_vector_type(8))) short short8;
typedef __attribute__((ext_vector_type(4))) float f32x4;

__device__ __forceinline__ float gelu_tanh(float v) {
  float u = 0.7978845608028654f * (v + 0.044715f * v * v * v);
  u = fminf(fmaxf(u, -10.f), 10.f);
  float t = __expf(2.f * u);
  return 0.5f * v * (1.0f + (t - 1.f) / (t + 1.f));
}

// RNE float->bf16
__device__ __forceinline__ ushort f2bf(float v) {
  union { float f; unsigned u; } c; c.f = v;
  unsigned r = (c.u + 0x7fffu + ((c.u >> 16) & 1u)) >> 16;
  return (ushort)r;
}
__device__ __forceinline__ float bf2f(ushort u) {
  union { unsigned u; float f; } c; c.u = ((unsigned)u) << 16;
  return c.f;
}
__device__ __forceinline__ uint packhl(float v) {
  ushort hi = f2bf(v);
  ushort lo = f2bf(v - bf2f(hi));
  return (uint)hi | ((uint)lo << 16);
}
__device__ __forceinline__ float unpackhl(uint u) {
  union { unsigned u; float f; } a, b;
  a.u = u << 16;
  b.u = u & 0xffff0000u;
  return a.f + b.f;
}

__device__ __forceinline__ uint prm(uint a, uint b, uint s) {
#if __has_builtin(__builtin_amdgcn_perm)
  return __builtin_amdgcn_perm(a, b, s);
#else
  uint r = 0;
  for (int i = 0; i < 4; ++i) {
    uint sel = (s >> (8 * i)) & 0xff;
    uint byte = sel < 4 ? (b >> (8 * sel)) & 0xff : (a >> (8 * (sel - 4))) & 0xff;
    r |= byte << (8 * i);
  }
  return r;
#endif
}

union S8U { uint u[4]; short8 s; };

// v0 = packed elems k..k+3, v1 = k+4..k+7 -> hi-frag / lo-frag short8
__device__ __forceinline__ void unpack_frag(uint4 v0, uint4 v1, short8& hi, short8& lo) {
  S8U h, l;
  h.u[0] = prm(v0.y, v0.x, 0x05040100u);
  l.u[0] = prm(v0.y, v0.x, 0x07060302u);
  h.u[1] = prm(v0.w, v0.z, 0x05040100u);
  l.u[1] = prm(v0.w, v0.z, 0x07060302u);
  h.u[2] = prm(v1.y, v1.x, 0x05040100u);
  l.u[2] = prm(v1.y, v1.x, 0x07060302u);
  h.u[3] = prm(v1.w, v1.z, 0x05040100u);
  l.u[3] = prm(v1.w, v1.z, 0x07060302u);
  hi = h.s;
  lo = l.s;
}

#define GLOAD_LDS16(gptr, ldsptr)                                                        \
  __builtin_amdgcn_global_load_lds((const __attribute__((address_space(1))) void*)(gptr), \
                                   (__attribute__((address_space(3))) void*)(ldsptr), 16, 0, 0)

// ============ 256x256 8-wave counted-vmcnt GEMM ============
// C = (Ahi+Alo)[M,K] @ (Bhi+Blo)[N,K]^T via 3 bf16 MFMA products, fp32 accum.
// A/B packed u32 (hi | lo<<16) per fp32 element. Strides in elements.
// MODE 1: gelu(v+bias) -> packed u32. MODE 2: v+bias -> packed u32.
// MODE 3: atomicAdd fp32 (dst prefilled with bias); K split by blockIdx.z.
template <int MODE>
__global__ __launch_bounds__(512, 2) void gemm_mfma256(const uint* __restrict__ A,
                                                       const uint* __restrict__ Bw,
                                                       const float* __restrict__ bias,
                                                       float* __restrict__ outF,
                                                       uint* __restrict__ outU,
                                                       int lda, int ldb, int ldc, int Ksz) {
  __shared__ uint sA[2][256 * 32];  // [buf][row 0..255][32 u32], 128B rows
  __shared__ uint sB[2][256 * 32];
  const int tid = threadIdx.x;
  const int w = tid >> 6;       // 0..7
  const int lane = tid & 63;
  const int wm = w >> 2;        // 0..1  (M half)
  const int wn = w & 3;         // 0..3  (N quarter)

  // bijective XCD swizzle over x-y plane (all grids have gx*gy % 8 == 0)
  const int gx = gridDim.x;
  const int flat = blockIdx.y * gx + blockIdx.x;
  const int q8 = (gx * (int)gridDim.y) >> 3;
  const int swz = (flat & 7) * q8 + (flat >> 3);
  const int bm = (swz / gx) * 256;
  const int bn = (swz % gx) * 256;
  const int kStart = blockIdx.z * Ksz;

  // staging: chunk c = i*8+w covers rows [c*8, c*8+8); lane l -> row c*8+(l>>3),
  // physical 16B-block l&7 sourced from logical block (l&7)^(l>>3)  (XOR swizzle)
  const int srow = lane >> 3;
  const int scol = ((lane & 7) ^ srow) << 2;  // u32 offset within 32-elem row
  const uint* Ab = A + (size_t)(bm + srow) * lda + kStart + scol;
  const uint* Bb = Bw + (size_t)(bn + srow) * ldb + kStart + scol;

#define STAGE(buf, kt)                                                         \
  do {                                                                         \
    _Pragma("unroll") for (int i_ = 0; i_ < 4; ++i_) {                         \
      const int c_ = i_ * 8 + w;                                               \
      GLOAD_LDS16(Ab + (size_t)(c_ * 8) * lda + (kt), &sA[buf][c_ * 256]);     \
      GLOAD_LDS16(Bb + (size_t)(c_ * 8) * ldb + (kt), &sB[buf][c_ * 256]);     \
    }                                                                          \
  } while (0)

  // fragment read constants (16x16x32: row = lane&15, k = 8*(lane>>4)+0..7)
  const int fr = lane & 15;
  const int s7 = fr & 7;
  const int kq = (lane >> 4) << 1;         // logical 16B-block index (even)
  const int p0 = ((kq ^ s7)) << 2;         // swizzled u32 offsets
  const int p1 = ((kq ^ s7) ^ 1) << 2;

  f32x4 acc[8][4] = {};
  const int NT = Ksz / 32;

  STAGE(0, 0);

  for (int t = 0; t < NT; ++t) {
    const int cur = t & 1;
    const int ktn = (t + 1 < NT) ? (t + 1) * 32 : 0;  // garbage-stage last iter (uniform vmcnt)
    STAGE(cur ^ 1, ktn);
    asm volatile("s_waitcnt vmcnt(8)" ::: "memory");  // tile t's 8 loads landed; t+1's in flight
    __builtin_amdgcn_s_barrier();
    __builtin_amdgcn_sched_barrier(0);

    // B fragments for all 4 ni (reused across phases)
    short8 bh[4], bl[4];
#pragma unroll
    for (int ni = 0; ni < 4; ++ni) {
      const uint* base = &sB[cur][(wn * 64 + ni * 16 + fr) * 32];
      uint4 v0 = *(const uint4*)(base + p0);
      uint4 v1 = *(const uint4*)(base + p1);
      unpack_frag(v0, v1, bh[ni], bl[ni]);
    }

#pragma unroll
    for (int ph = 0; ph < 4; ++ph) {  // phase: mi pair {2ph, 2ph+1}
      short8 ah[2], al[2];
#pragma unroll
      for (int m2 = 0; m2 < 2; ++m2) {
        const uint* base = &sA[cur][(wm * 128 + (ph * 2 + m2) * 16 + fr) * 32];
        uint4 v0 = *(const uint4*)(base + p0);
        uint4 v1 = *(const uint4*)(base + p1);
        unpack_frag(v0, v1, ah[m2], al[m2]);
      }
      __builtin_amdgcn_s_setprio(1);
#pragma unroll
      for (int m2 = 0; m2 < 2; ++m2) {
        const int mi = ph * 2 + m2;
#pragma unroll
        for (int ni = 0; ni < 4; ++ni) {
          acc[mi][ni] = __builtin_amdgcn_mfma_f32_16x16x32_bf16(ah[m2], bh[ni], acc[mi][ni], 0, 0, 0);
          acc[mi][ni] = __builtin_amdgcn_mfma_f32_16x16x32_bf16(ah[m2], bl[ni], acc[mi][ni], 0, 0, 0);
          acc[mi][ni] = __builtin_amdgcn_mfma_f32_16x16x32_bf16(al[m2], bh[ni], acc[mi][ni], 0, 0, 0);
        }
      }
      __builtin_amdgcn_s_setprio(0);
      __builtin_amdgcn_sched_barrier(0);
    }
    __builtin_amdgcn_sched_barrier(0);
    __builtin_amdgcn_s_barrier();  // all waves done reading buf cur before next STAGE overwrites
  }
#undef STAGE
  asm volatile("s_waitcnt vmcnt(0)" ::: "memory");  // drain garbage stage before LDS dealloc

  const int erow = (lane >> 4) << 2;  // C/D: col=lane&15, row=(lane>>4)*4+e
#pragma unroll
  for (int ni = 0; ni < 4; ++ni) {
    const int col = bn + wn * 64 + ni * 16 + fr;
    const float bv = (MODE == 3) ? 0.f : bias[col];
#pragma unroll
    for (int mi = 0; mi < 8; ++mi) {
#pragma unroll
      for (int e = 0; e < 4; ++e) {
        const int row = bm + wm * 128 + mi * 16 + erow + e;
        float v = acc[mi][ni][e] + bv;
        if (MODE == 1) {
          outU[(size_t)row * ldc + col] = packhl(gelu_tanh(v));
        } else if (MODE == 2) {
          outU[(size_t)row * ldc + col] = packhl(v);
        } else {
          atomicAdd(&outF[(size_t)row * ldc + col], v);
        }
      }
    }
  }
}

// W[K][N] fp32 -> packed-hi/lo u32, transposed to [N][K]
__global__ __launch_bounds__(256) void convert_w_t(const float* __restrict__ W,
                                                   uint* __restrict__ WT, int K, int N) {
  __shared__ float tile[32][33];
  const int kb = blockIdx.y * 32, nb = blockIdx.x * 32;
  const int tr = threadIdx.x >> 5;
  const int tc = threadIdx.x & 31;
#pragma unroll
  for (int p = 0; p < 4; ++p) {
    int r = tr + p * 8;
    tile[r][tc] = W[(size_t)(kb + r) * N + nb + tc];
  }
  __syncthreads();
#pragma unroll
  for (int p = 0; p < 4; ++p) {
    int n = tr + p * 8;
    WT[(size_t)(nb + n) * K + kb + tc] = packhl(tile[tc][n]);
  }
}

__global__ __launch_bounds__(256) void fill_bias_kernel(float* __restrict__ dst,
                                                        const float* __restrict__ bias) {
  const size_t i4 = (size_t)blockIdx.x * 256 + threadIdx.x;  // BS*H/4 total
  const int c4 = (int)(i4 % (H / 4));
  ((float4*)dst)[i4] = ((const float4*)bias)[c4];
}

// One block per (batch, head). qkv packed u32 [row][3H]; writes output
// IN PLACE into the Q-slot columns (block reads all its Q/K/V to LDS first).
__global__ __launch_bounds__(256) void attn_kernel(uint* __restrict__ qkv,
                                                   const int* __restrict__ mask) {
  __shared__ float smem[64 * 64 + 64 * 66 + 64 * 64];  // Qs | KsT | Vs ; Ps aliases
  float (*Qs)[64] = (float (*)[64])smem;
  float (*KsT)[66] = (float (*)[66])(smem + 64 * 64);
  float (*Vs)[64] = (float (*)[64])(smem + 64 * 64 + 64 * 66);
  float (*Ps)[65] = (float (*)[65])smem;

  const int bl = blockIdx.x / NH;
  const int hh = blockIdx.x % NH;
  const int tid = threadIdx.x;
  const int lane = tid & 63;
  const int w = tid >> 6;

  for (int i = 0; i < 16; ++i) {
    int idx = tid + i * 256;
    int r = idx >> 6, d = idx & 63;
    size_t base = (size_t)(bl * 64 + r) * (3 * H) + hh * 64 + d;
    Qs[r][d] = unpackhl(qkv[base]);
    KsT[d][r] = unpackhl(qkv[base + H]);
    Vs[r][d] = unpackhl(qkv[base + 2 * H]);
  }
  __syncthreads();

  float sc[16];
#pragma unroll
  for (int i = 0; i < 16; ++i) sc[i] = 0.f;
  for (int d = 0; d < 64; ++d) {
    float kv = KsT[d][lane];
#pragma unroll
    for (int i = 0; i < 16; ++i) sc[i] += Qs[w + 4 * i][d] * kv;
  }
  __syncthreads();
  float biask = (1.0f - (float)mask[bl * S + lane]) * -1e9f;
#pragma unroll
  for (int i = 0; i < 16; ++i) Ps[w + 4 * i][lane] = sc[i] * 0.125f + biask;
  __syncthreads();

  if (tid < 64) {
    int qr = tid;
    float mx = -1e30f;
    for (int k = 0; k < 64; ++k) mx = fmaxf(mx, Ps[qr][k]);
    float sum = 0.f;
    for (int k = 0; k < 64; ++k) {
      float e = expf(Ps[qr][k] - mx);
      Ps[qr][k] = e;
      sum += e;
    }
    float inv = 1.0f / sum;
    for (int k = 0; k < 64; ++k) Ps[qr][k] *= inv;
  }
  __syncthreads();

  float o[16];
#pragma unroll
  for (int i = 0; i < 16; ++i) o[i] = 0.f;
  for (int k = 0; k < 64; ++k) {
    float vv = Vs[k][lane];
#pragma unroll
    for (int i = 0; i < 16; ++i) o[i] += Ps[w + 4 * i][k] * vv;
  }
#pragma unroll
  for (int i = 0; i < 16; ++i) {
    int qr = w + 4 * i;
    qkv[(size_t)(bl * 64 + qr) * (3 * H) + hh * 64 + lane] = packhl(o[i]);
  }
}

__global__ __launch_bounds__(256) void embed_ln_kernel(const int* __restrict__ ids,
                                                       const float* __restrict__ we,
                                                       const float* __restrict__ pe,
                                                       const float* __restrict__ te,
                                                       const float* __restrict__ g,
                                                       const float* __restrict__ bta,
                                                       uint* __restrict__ xhl) {
  __shared__ float buf[H];
  __shared__ float red[256];
  const int row = blockIdx.x;
  const int s = row % S;
  const int tid = threadIdx.x;
  const int id = ids[row];
  float local = 0.f;
  for (int i = tid; i < H; i += 256) {
    float v = we[(size_t)id * H + i] + pe[(size_t)s * H + i] + te[i];
    buf[i] = v;
    local += v;
  }
  red[tid] = local;
  __syncthreads();
  for (int st = 128; st > 0; st >>= 1) {
    if (tid < st) red[tid] += red[tid + st];
    __syncthreads();
  }
  float mean = red[0] * (1.0f / H);
  __syncthreads();
  float ls = 0.f;
  for (int i = tid; i < H; i += 256) {
    float d = buf[i] - mean;
    ls += d * d;
  }
  red[tid] = ls;
  __syncthreads();
  for (int st = 128; st > 0; st >>= 1) {
    if (tid < st) red[tid] += red[tid + st];
    __syncthreads();
  }
  float inv = 1.0f / sqrtf(red[0] * (1.0f / H) + 1e-12f);
  for (int i = tid; i < H; i += 256) {
    float o = (buf[i] - mean) * inv * g[i] + bta[i];
    xhl[(size_t)row * H + i] = packhl(o);
  }
}

// x = LayerNorm(unpack(xhl) + y) * g + b ; write packed hi/lo back to xhl
__global__ __launch_bounds__(256) void add_ln_kernel(uint* __restrict__ xhl,
                                                     const float* __restrict__ y,
                                                     const float* __restrict__ g,
                                                     const float* __restrict__ bta) {
  __shared__ float buf[H];
  __shared__ float red[256];
  const size_t row = blockIdx.x;
  const int tid = threadIdx.x;
  float local = 0.f;
  for (int i = tid; i < H; i += 256) {
    float v = unpackhl(xhl[row * H + i]) + y[row * H + i];
    buf[i] = v;
    local += v;
  }
  red[tid] = local;
  __syncthreads();
  for (int st = 128; st > 0; st >>= 1) {
    if (tid < st) red[tid] += red[tid + st];
    __syncthreads();
  }
  float mean = red[0] * (1.0f / H);
  __syncthreads();
  float ls = 0.f;
  for (int i = tid; i < H; i += 256) {
    float d = buf[i] - mean;
    ls += d * d;
  }
  red[tid] = ls;
  __syncthreads();
  for (int st = 128; st > 0; st >>= 1) {
    if (tid < st) red[tid] += red[tid + st];
    __syncthreads();
  }
  float inv = 1.0f / sqrtf(red[0] * (1.0f / H) + 1e-12f);
  for (int i = tid; i < H; i += 256) {
    float o = (buf[i] - mean) * inv * g[i] + bta[i];
    xhl[row * H + i] = packhl(o);
  }
}

__global__ __launch_bounds__(256) void fc_kernel(const uint* __restrict__ xhl,
                                                 const float* __restrict__ w,
                                                 const float* __restrict__ bias,
                                                 float* __restrict__ logits) {
  __shared__ float xs[H];
  const size_t row = blockIdx.x;
  const int tid = threadIdx.x;
  for (int i = tid; i < H; i += 256) xs[i] = unpackhl(xhl[row * H + i]);
  __syncthreads();
  const int j = tid >> 4, l = tid & 15;
  if (j < T) {
    float s = 0.f;
    for (int k = l; k < H; k += 16) s += xs[k] * w[(size_t)k * T + j];
#pragma unroll
    for (int d = 8; d > 0; d >>= 1) s += __shfl_down(s, d, 16);
    if (l == 0) logits[row * T + j] = s + bias[j];
  }
}

__global__ __launch_bounds__(64) void crf_llh_kernel(const float* __restrict__ em,
                                                     const int* __restrict__ label,
                                                     const int* __restrict__ mask,
                                                     const float* __restrict__ start,
                                                     const float* __restrict__ endw,
                                                     const float* __restrict__ trans,
                                                     float* __restrict__ llh) {
  const int b = blockIdx.x;
  const int c = threadIdx.x;
  __shared__ float alpha[T];
  __shared__ float tr[T][T];
  for (int i = c; i < T * T; i += 64) tr[i / T][i % T] = trans[i];
  if (c < T) alpha[c] = start[c] + em[(size_t)b * S * T + c];
  __syncthreads();
  for (int s = 1; s < S; ++s) {
    float a = 0.f;
    if (c < T) {
      float mx = -1e30f;
      for (int p = 0; p < T; ++p) mx = fmaxf(mx, alpha[p] + tr[p][c]);
      float sum = 0.f;
      for (int p = 0; p < T; ++p) sum += expf(alpha[p] + tr[p][c] - mx);
      a = mx + logf(sum) + em[((size_t)b * S + s) * T + c];
    }
    __syncthreads();
    if (c < T) {
      float m = (float)mask[b * S + s];
      alpha[c] = (m > 0.f) ? a : alpha[c];
    }
    __syncthreads();
  }
  if (c == 0) {
    float mx = -1e30f;
    for (int p = 0; p < T; ++p) mx = fmaxf(mx, alpha[p] + endw[p]);
    float sum = 0.f;
    for (int p = 0; p < T; ++p) sum += expf(alpha[p] + endw[p] - mx);
    float denom = mx + logf(sum);

    int t0 = label[b * S];
    float score = start[t0] + em[(size_t)b * S * T + t0];
    int prev = t0;
    for (int s = 1; s < S; ++s) {
      int tc = label[b * S + s];
      float m = (float)mask[b * S + s];
      score += (tr[prev][tc] + em[((size_t)b * S + s) * T + tc]) * m;
      prev = tc;
    }
    int msum = 0;
    for (int s = 0; s < S; ++s) msum += mask[b * S + s];
    score += endw[label[b * S + (msum - 1)]];
    llh[b] = score - denom;
  }
}

__global__ __launch_bounds__(256) void loss_kernel(const float* __restrict__ llh,
                                                   float* __restrict__ out) {
  __shared__ float red[256];
  const int tid = threadIdx.x;
  red[tid] = llh[tid];  // B == 256
  __syncthreads();
  for (int st = 128; st > 0; st >>= 1) {
    if (tid < st) red[tid] += red[tid + st];
    __syncthreads();
  }
  if (tid == 0) out[BS] = -red[0] * (1.0f / B);
}

__global__ __launch_bounds__(64) void viterbi_kernel(const float* __restrict__ em,
                                                     const int* __restrict__ mask,
                                                     const float* __restrict__ start,
                                                     const float* __restrict__ endw,
                                                     const float* __restrict__ trans,
                                                     float* __restrict__ pred) {
  const int b = blockIdx.x;
  const int c = threadIdx.x;
  __shared__ float sc[T];
  __shared__ float tr[T][T];
  __shared__ int hist[S - 1][T];
  for (int i = c; i < T * T; i += 64) tr[i / T][i % T] = trans[i];
  if (c < T) sc[c] = start[c] + em[(size_t)b * S * T + c];
  __syncthreads();
  for (int s = 1; s < S; ++s) {
    float bestv = -1e30f;
    int bestp = 0;
    if (c < T) {
      for (int p = 0; p < T; ++p) {
        float v = sc[p] + tr[p][c];
        if (v > bestv) { bestv = v; bestp = p; }
      }
      hist[s - 1][c] = bestp;
    }
    __syncthreads();
    if (c < T) {
      float m = (float)mask[b * S + s];
      sc[c] = (m > 0.f) ? (bestv + em[((size_t)b * S + s) * T + c]) : sc[c];
    }
    __syncthreads();
  }
  if (c == 0) {
    float bv = -1e30f;
    int last = 0;
    for (int p = 0; p < T; ++p) {
      float v = sc[p] + endw[p];
      if (v > bv) { bv = v; last = p; }
    }
    pred[b * S + (S - 1)] = (float)last;
    int t = last;
    for (int hs = S - 2; hs >= 0; --hs) {
      if (mask[b * S + hs + 1] > 0) t = hist[hs][t];
      pred[b * S + hs] = (float)t;
    }
  }
}

}  // namespace

extern "C" void kernel_launch(void* const* d_in, const int* in_sizes, int n_in,
                              void* d_out, int out_size, void* d_ws, size_t ws_size,
                              hipStream_t stream) {
  (void)in_sizes; (void)n_in; (void)out_size; (void)ws_size;
  const int* input_ids = (const int*)d_in[0];
  const int* attn_mask = (const int*)d_in[1];
  const int* label = (const int*)d_in[2];
  const float* word_emb = (const float*)d_in[3];
  const float* pos_emb = (const float*)d_in[4];
  const float* tok_emb = (const float*)d_in[5];
  const float* eg = (const float*)d_in[6];
  const float* ebt = (const float*)d_in[7];
  const float* Wqkv = (const float*)d_in[8];
  const float* bqkv = (const float*)d_in[9];
  const float* Wo = (const float*)d_in[10];
  const float* bo = (const float*)d_in[11];
  const float* ln1g = (const float*)d_in[12];
  const float* ln1b = (const float*)d_in[13];
  const float* W1 = (const float*)d_in[14];
  const float* b1 = (const float*)d_in[15];
  const float* W2 = (const float*)d_in[16];
  const float* b2 = (const float*)d_in[17];
  const float* ln2g = (const float*)d_in[18];
  const float* ln2b = (const float*)d_in[19];
  const float* fc_w = (const float*)d_in[20];
  const float* fc_b = (const float*)d_in[21];
  const float* crf_start = (const float*)d_in[22];
  const float* crf_end = (const float*)d_in[23];
  const float* crf_trans = (const float*)d_in[24];
  float* out = (float*)d_out;

  // ---- workspace layout (280.7 MB == proven round-2/3 footprint) ----
  char* p = (char*)d_ws;
  uint* xhl = (uint*)p;        p += (size_t)BS * H * 4;          // 50.3 MB packed residual
  float* tmpA = (float*)p;     p += (size_t)BS * H * 4;          // 50.3 MB fp32 (atomic dst)
  uint* wQ = (uint*)p;         p += (size_t)3 * H * H * 4;       // 7.1 MB  [3H][H]
  uint* wO = (uint*)p;         p += (size_t)H * H * 4;           // 2.4 MB  [H][H]
  uint* wF1 = (uint*)p;        p += (size_t)F * H * 4;           // 9.4 MB  [F][H]
  uint* wF2 = (uint*)p;        p += (size_t)H * F * 4;           // 9.4 MB  [H][F]
  uint* big = (uint*)p;        p += (size_t)BS * 3 * H * 4;      // 151.0 MB
  float* logits = (float*)p;   p += (size_t)BS * T * 4;
  float* llh = (float*)p;      p += (size_t)B * 4;
  uint* qkvU = big;   // [BS][3H] packed; attn out lands in Q-slot cols
  uint* hU = big;     // [RC][F] packed (FFN phase, per chunk)

  embed_ln_kernel<<<BS, 256, 0, stream>>>(input_ids, word_emb, pos_emb, tok_emb, eg, ebt, xhl);

  for (int l = 0; l < L; ++l) {
    const float* wqkv_l = Wqkv + (size_t)l * H * 3 * H;
    const float* bqkv_l = bqkv + (size_t)l * 3 * H;
    const float* wo_l = Wo + (size_t)l * H * H;
    const float* bo_l = bo + (size_t)l * H;
    const float* g1 = ln1g + (size_t)l * H;
    const float* be1 = ln1b + (size_t)l * H;
    const float* w1_l = W1 + (size_t)l * H * F;
    const float* b1_l = b1 + (size_t)l * F;
    const float* w2_l = W2 + (size_t)l * F * H;
    const float* b2_l = b2 + (size_t)l * H;
    const float* g2 = ln2g + (size_t)l * H;
    const float* be2 = ln2b + (size_t)l * H;

    convert_w_t<<<dim3(3 * H / 32, H / 32), 256, 0, stream>>>(wqkv_l, wQ, H, 3 * H);
    convert_w_t<<<dim3(H / 32, H / 32), 256, 0, stream>>>(wo_l, wO, H, H);
    convert_w_t<<<dim3(F / 32, H / 32), 256, 0, stream>>>(w1_l, wF1, H, F);
    convert_w_t<<<dim3(H / 32, F / 32), 256, 0, stream>>>(w2_l, wF2, F, H);

    // ---- attention block ----
    // QKV: [BS,H] @ [H,3H] -> qkvU   grid 9x64 = 576
    gemm_mfma256<2><<<dim3(3 * H / 256, BS / 256, 1), 512, 0, stream>>>(
        xhl, wQ, bqkv_l, nullptr, qkvU, H, H, 3 * H, H);
    attn_kernel<<<B * NH, 256, 0, stream>>>(qkvU, attn_mask);
    // Wo: [BS,H(Q-slot)] @ [H,H] -> tmpA (atomic, z=4)   grid 3x64x4 = 768
    fill_bias_kernel<<<BS * H / 4 / 256, 256, 0, stream>>>(tmpA, bo_l);
    gemm_mfma256<3><<<dim3(H / 256, BS / 256, 4), 512, 0, stream>>>(
        qkvU, wO, nullptr, tmpA, nullptr, 3 * H, H, H, H / 4);
    add_ln_kernel<<<BS, 256, 0, stream>>>(xhl, tmpA, g1, be1);

    // ---- FFN block ----
    fill_bias_kernel<<<BS * H / 4 / 256, 256, 0, stream>>>(tmpA, b2_l);
    for (int ch = 0; ch < NCH; ++ch) {
      // FFN1: [RC,H] @ [H,F] -> hU (gelu, packed)   grid 12x32 = 384
      gemm_mfma256<1><<<dim3(F / 256, RC / 256, 1), 512, 0, stream>>>(
          xhl + (size_t)ch * RC * H, wF1, b1_l, nullptr, hU, H, H, F, H);
      // FFN2: [RC,F] @ [F,H] -> tmpA (atomic, z=4)  grid 3x32x4 = 384
      gemm_mfma256<3><<<dim3(H / 256, RC / 256, 4), 512, 0, stream>>>(
          hU, wF2, nullptr, tmpA + (size_t)ch * RC * H, nullptr, F, F, H, F / 4);
    }
    add_ln_kernel<<<BS, 256, 0, stream>>>(xhl, tmpA, g2, be2);
  }

  fc_kernel<<<BS, 256, 0, stream>>>(xhl, fc_w, fc_b, logits);
  crf_llh_kernel<<<B, 64, 0, stream>>>(logits, label, attn_mask, crf_start, crf_end, crf_trans, llh);
  loss_kernel<<<1, 256, 0, stream>>>(llh, out);
  viterbi_kernel<<<B, 64, 0, stream>>>(logits, attn_mask, crf_start, crf_end, crf_trans, out);
}

// Round 5
// 14520.375 us; speedup vs baseline: 1.1319x; 1.1319x over previous
//
#include <hip/hip_runtime.h>
#include <hip/hip_bf16.h>
#include <math.h>

namespace {

constexpr int B = 256, S = 64, H = 768, L = 12, NH = 12, F = 3072, T = 11;
constexpr int BS = B * S;   // 16384 rows
constexpr int RC = 8192;    // rows per FFN chunk
constexpr int NCH = BS / RC;

typedef __attribute__((ext_vector_type(8))) short short8;
typedef __attribute__((ext_vector_type(4))) float f32x4;

__device__ __forceinline__ float gelu_tanh(float v) {
  float u = 0.7978845608028654f * (v + 0.044715f * v * v * v);
  u = fminf(fmaxf(u, -10.f), 10.f);
  float t = __expf(2.f * u);
  return 0.5f * v * (1.0f + (t - 1.f) / (t + 1.f));
}

// RNE float->bf16
__device__ __forceinline__ ushort f2bf(float v) {
  union { float f; unsigned u; } c; c.f = v;
  unsigned r = (c.u + 0x7fffu + ((c.u >> 16) & 1u)) >> 16;
  return (ushort)r;
}
__device__ __forceinline__ float bf2f(ushort u) {
  union { unsigned u; float f; } c; c.u = ((unsigned)u) << 16;
  return c.f;
}
__device__ __forceinline__ uint packhl(float v) {
  ushort hi = f2bf(v);
  ushort lo = f2bf(v - bf2f(hi));
  return (uint)hi | ((uint)lo << 16);
}
__device__ __forceinline__ float unpackhl(uint u) {
  union { unsigned u; float f; } a, b;
  a.u = u << 16;
  b.u = u & 0xffff0000u;
  return a.f + b.f;
}

__device__ __forceinline__ uint prm(uint a, uint b, uint s) {
#if __has_builtin(__builtin_amdgcn_perm)
  return __builtin_amdgcn_perm(a, b, s);
#else
  uint r = 0;
  for (int i = 0; i < 4; ++i) {
    uint sel = (s >> (8 * i)) & 0xff;
    uint byte = sel < 4 ? (b >> (8 * sel)) & 0xff : (a >> (8 * (sel - 4))) & 0xff;
    r |= byte << (8 * i);
  }
  return r;
#endif
}

union S8U { uint u[4]; short8 s; };

// v0 = packed elems k..k+3, v1 = k+4..k+7 -> hi-frag / lo-frag short8
__device__ __forceinline__ void unpack_frag(uint4 v0, uint4 v1, short8& hi, short8& lo) {
  S8U h, l;
  h.u[0] = prm(v0.y, v0.x, 0x05040100u);
  l.u[0] = prm(v0.y, v0.x, 0x07060302u);
  h.u[1] = prm(v0.w, v0.z, 0x05040100u);
  l.u[1] = prm(v0.w, v0.z, 0x07060302u);
  h.u[2] = prm(v1.y, v1.x, 0x05040100u);
  l.u[2] = prm(v1.y, v1.x, 0x07060302u);
  h.u[3] = prm(v1.w, v1.z, 0x05040100u);
  l.u[3] = prm(v1.w, v1.z, 0x07060302u);
  hi = h.s;
  lo = l.s;
}

#define GLOAD_LDS16(gptr, ldsptr)                                                        \
  __builtin_amdgcn_global_load_lds((const __attribute__((address_space(1))) void*)(gptr), \
                                   (__attribute__((address_space(3))) void*)(ldsptr), 16, 0, 0)

// ============ 128x256 8-wave counted-vmcnt GEMM ============
// C = (Ahi+Alo)[M,K] @ (Bhi+Blo)[N,K]^T via 3 bf16 MFMA products, fp32 accum.
// A: packed u32 (hi | lo<<16) per fp32 element, row stride lda (u32).
// B: planar block-interleaved bf16 [N][2K]: k-block j -> [j*64 .. +31]=hi, [+32..+63]=lo.
// MODE 1: gelu(v+bias) -> packed u32. MODE 2: v+bias -> packed u32.
// MODE 3: atomicAdd fp32 (dst prefilled with bias); K split by blockIdx.z (ktiles each).
template <int MODE>
__global__ __launch_bounds__(512, 2) void gemm_mfma(const uint* __restrict__ A,
                                                    const ushort* __restrict__ Bw,
                                                    const float* __restrict__ bias,
                                                    float* __restrict__ outF,
                                                    uint* __restrict__ outU,
                                                    int lda, int ldb2, int ldc, int ktiles) {
  __shared__ uint sA[2][128 * 32];     // [buf][row][32 u32]  128B rows
  __shared__ ushort sB[2][256 * 64];   // [buf][row][64 bf16] 128B rows
  const int tid = threadIdx.x;
  const int w = tid >> 6;       // 0..7
  const int lane = tid & 63;
  const int wm = w >> 2;        // 0..1  (M half, 64 rows)
  const int wn = w & 3;         // 0..3  (N quarter, 64 cols)

  // bijective XCD swizzle over the full grid (all totals % 8 == 0)
  const int gx = gridDim.x, gy = gridDim.y;
  const int flat = ((int)blockIdx.z * gy + blockIdx.y) * gx + blockIdx.x;
  const int q8 = (gx * gy * (int)gridDim.z) >> 3;
  const int swz = (flat & 7) * q8 + (flat >> 3);
  const int bx = swz % gx;
  const int by = (swz / gx) % gy;
  const int bz = swz / (gx * gy);
  const int bm = by * 128;
  const int bn = bx * 256;
  const int kA0 = bz * ktiles * 32;   // u32 elements
  const int kB0 = bz * ktiles * 64;   // ushort elements

  // staging source addressing: within each 8-row/1KB chunk, lane l -> row +l/8,
  // phys 16B-block l%8 sourced from logical block (l%8)^(l/8)  (XOR swizzle)
  const int srow = lane >> 3;
  const int sblk = (lane & 7) ^ srow;
  const uint* Ab = A + (size_t)(bm + w * 16 + srow) * lda + kA0 + sblk * 4;
  const ushort* Bb = Bw + (size_t)(bn + w * 32 + srow) * ldb2 + kB0 + sblk * 8;

#define STAGE(buf, tk)                                                          \
  do {                                                                          \
    GLOAD_LDS16(Ab + (size_t)(tk) * 32, &sA[buf][(w * 16) * 32]);               \
    GLOAD_LDS16(Ab + (size_t)(tk) * 32 + (size_t)8 * lda,                       \
                &sA[buf][(w * 16 + 8) * 32]);                                   \
    _Pragma("unroll") for (int c_ = 0; c_ < 4; ++c_) {                          \
      GLOAD_LDS16(Bb + (size_t)(tk) * 64 + (size_t)(c_ * 8) * ldb2,             \
                  &sB[buf][(w * 32 + c_ * 8) * 64]);                            \
    }                                                                           \
  } while (0)

  // fragment read constants (16x16x32: row = lane&15, k = 8*(lane>>4)+0..7)
  const int fr = lane & 15;
  const int s7 = fr & 7;
  const int jb = lane >> 4;             // 0..3
  const int p0 = ((jb << 1) ^ s7) << 2; // A: swizzled u32 offsets (16B blocks)
  const int p1 = (((jb << 1) ^ s7) ^ 1) << 2;
  const int bhOff = ((jb) ^ s7) << 3;       // B hi: blocks 0..3
  const int blOff = ((4 + jb) ^ s7) << 3;   // B lo: blocks 4..7

  f32x4 acc[4][4] = {};
  const int NT = ktiles;

  STAGE(0, 0);  // prologue

  for (int t = 0; t < NT; ++t) {
    const int cur = t & 1;
    const int tkn = (t + 1 < NT) ? (t + 1) : 0;  // garbage-restage on last iter
    STAGE(cur ^ 1, tkn);
    asm volatile("s_waitcnt vmcnt(6)" ::: "memory");  // tile t's 6 loads landed
    __builtin_amdgcn_s_barrier();

    // B fragments: direct short8, no unpack
    short8 bh[4], bl[4];
#pragma unroll
    for (int ni = 0; ni < 4; ++ni) {
      const ushort* baseB = &sB[cur][(wn * 64 + ni * 16 + fr) * 64];
      bh[ni] = *(const short8*)(baseB + bhOff);
      bl[ni] = *(const short8*)(baseB + blOff);
    }
    __builtin_amdgcn_s_setprio(1);
#pragma unroll
    for (int mi = 0; mi < 4; ++mi) {
      const uint* baseA = &sA[cur][(wm * 64 + mi * 16 + fr) * 32];
      uint4 v0 = *(const uint4*)(baseA + p0);
      uint4 v1 = *(const uint4*)(baseA + p1);
      short8 ah, al;
      unpack_frag(v0, v1, ah, al);
#pragma unroll
      for (int ni = 0; ni < 4; ++ni) {
        acc[mi][ni] = __builtin_amdgcn_mfma_f32_16x16x32_bf16(ah, bh[ni], acc[mi][ni], 0, 0, 0);
        acc[mi][ni] = __builtin_amdgcn_mfma_f32_16x16x32_bf16(ah, bl[ni], acc[mi][ni], 0, 0, 0);
        acc[mi][ni] = __builtin_amdgcn_mfma_f32_16x16x32_bf16(al, bh[ni], acc[mi][ni], 0, 0, 0);
      }
    }
    __builtin_amdgcn_s_setprio(0);
    asm volatile("s_waitcnt lgkmcnt(0)" ::: "memory");  // all LDS reads of buf cur done
    __builtin_amdgcn_s_barrier();
    __builtin_amdgcn_sched_barrier(0);  // pin: next STAGE stays after this barrier
  }
#undef STAGE
  asm volatile("s_waitcnt vmcnt(0)" ::: "memory");  // drain garbage stage

  const int erow = jb << 2;  // C/D: col=lane&15, row=(lane>>4)*4+e
#pragma unroll
  for (int ni = 0; ni < 4; ++ni) {
    const int col = bn + wn * 64 + ni * 16 + fr;
    const float bv = (MODE == 3) ? 0.f : bias[col];
#pragma unroll
    for (int mi = 0; mi < 4; ++mi) {
#pragma unroll
      for (int e = 0; e < 4; ++e) {
        const int row = bm + wm * 64 + mi * 16 + erow + e;
        float v = acc[mi][ni][e] + bv;
        if (MODE == 1) {
          outU[(size_t)row * ldc + col] = packhl(gelu_tanh(v));
        } else if (MODE == 2) {
          outU[(size_t)row * ldc + col] = packhl(v);
        } else {
          atomicAdd(&outF[(size_t)row * ldc + col], v);
        }
      }
    }
  }
}

// W[K][N] fp32 -> planar block-interleaved bf16 [N][2K]
__global__ __launch_bounds__(256) void convert_w_t(const float* __restrict__ W,
                                                   ushort* __restrict__ WI, int K, int N) {
  __shared__ float tile[32][33];
  const int kb = blockIdx.y * 32, nb = blockIdx.x * 32;
  const int tr = threadIdx.x >> 5;
  const int tc = threadIdx.x & 31;
#pragma unroll
  for (int p = 0; p < 4; ++p) {
    int r = tr + p * 8;
    tile[r][tc] = W[(size_t)(kb + r) * N + nb + tc];
  }
  __syncthreads();
  const int kblk = kb >> 5;  // kb multiple of 32
#pragma unroll
  for (int p = 0; p < 4; ++p) {
    int n = tr + p * 8;
    float v = tile[tc][n];
    ushort hi = f2bf(v);
    ushort lo = f2bf(v - bf2f(hi));
    size_t o = (size_t)(nb + n) * (2 * K) + (size_t)kblk * 64 + tc;
    WI[o] = hi;
    WI[o + 32] = lo;
  }
}

__global__ __launch_bounds__(256) void fill_bias_kernel(float* __restrict__ dst,
                                                        const float* __restrict__ bias) {
  const size_t i4 = (size_t)blockIdx.x * 256 + threadIdx.x;  // BS*H/4 total
  const int c4 = (int)(i4 % (H / 4));
  ((float4*)dst)[i4] = ((const float4*)bias)[c4];
}

// One block per (batch, head). qkv packed u32 [row][3H]; writes output
// IN PLACE into the Q-slot columns (block reads all its Q/K/V to LDS first).
__global__ __launch_bounds__(256) void attn_kernel(uint* __restrict__ qkv,
                                                   const int* __restrict__ mask) {
  __shared__ float smem[64 * 64 + 64 * 66 + 64 * 64];  // Qs | KsT | Vs ; Ps aliases
  float (*Qs)[64] = (float (*)[64])smem;
  float (*KsT)[66] = (float (*)[66])(smem + 64 * 64);
  float (*Vs)[64] = (float (*)[64])(smem + 64 * 64 + 64 * 66);
  float (*Ps)[65] = (float (*)[65])smem;

  const int bl = blockIdx.x / NH;
  const int hh = blockIdx.x % NH;
  const int tid = threadIdx.x;
  const int lane = tid & 63;
  const int w = tid >> 6;

  for (int i = 0; i < 16; ++i) {
    int idx = tid + i * 256;
    int r = idx >> 6, d = idx & 63;
    size_t base = (size_t)(bl * 64 + r) * (3 * H) + hh * 64 + d;
    Qs[r][d] = unpackhl(qkv[base]);
    KsT[d][r] = unpackhl(qkv[base + H]);
    Vs[r][d] = unpackhl(qkv[base + 2 * H]);
  }
  __syncthreads();

  float sc[16];
#pragma unroll
  for (int i = 0; i < 16; ++i) sc[i] = 0.f;
  for (int d = 0; d < 64; ++d) {
    float kv = KsT[d][lane];
#pragma unroll
    for (int i = 0; i < 16; ++i) sc[i] += Qs[w + 4 * i][d] * kv;
  }
  __syncthreads();
  float biask = (1.0f - (float)mask[bl * S + lane]) * -1e9f;
#pragma unroll
  for (int i = 0; i < 16; ++i) Ps[w + 4 * i][lane] = sc[i] * 0.125f + biask;
  __syncthreads();

  if (tid < 64) {
    int qr = tid;
    float mx = -1e30f;
    for (int k = 0; k < 64; ++k) mx = fmaxf(mx, Ps[qr][k]);
    float sum = 0.f;
    for (int k = 0; k < 64; ++k) {
      float e = expf(Ps[qr][k] - mx);
      Ps[qr][k] = e;
      sum += e;
    }
    float inv = 1.0f / sum;
    for (int k = 0; k < 64; ++k) Ps[qr][k] *= inv;
  }
  __syncthreads();

  float o[16];
#pragma unroll
  for (int i = 0; i < 16; ++i) o[i] = 0.f;
  for (int k = 0; k < 64; ++k) {
    float vv = Vs[k][lane];
#pragma unroll
    for (int i = 0; i < 16; ++i) o[i] += Ps[w + 4 * i][k] * vv;
  }
#pragma unroll
  for (int i = 0; i < 16; ++i) {
    int qr = w + 4 * i;
    qkv[(size_t)(bl * 64 + qr) * (3 * H) + hh * 64 + lane] = packhl(o[i]);
  }
}

__global__ __launch_bounds__(256) void embed_ln_kernel(const int* __restrict__ ids,
                                                       const float* __restrict__ we,
                                                       const float* __restrict__ pe,
                                                       const float* __restrict__ te,
                                                       const float* __restrict__ g,
                                                       const float* __restrict__ bta,
                                                       uint* __restrict__ xhl) {
  __shared__ float buf[H];
  __shared__ float red[256];
  const int row = blockIdx.x;
  const int s = row % S;
  const int tid = threadIdx.x;
  const int id = ids[row];
  float local = 0.f;
  for (int i = tid; i < H; i += 256) {
    float v = we[(size_t)id * H + i] + pe[(size_t)s * H + i] + te[i];
    buf[i] = v;
    local += v;
  }
  red[tid] = local;
  __syncthreads();
  for (int st = 128; st > 0; st >>= 1) {
    if (tid < st) red[tid] += red[tid + st];
    __syncthreads();
  }
  float mean = red[0] * (1.0f / H);
  __syncthreads();
  float ls = 0.f;
  for (int i = tid; i < H; i += 256) {
    float d = buf[i] - mean;
    ls += d * d;
  }
  red[tid] = ls;
  __syncthreads();
  for (int st = 128; st > 0; st >>= 1) {
    if (tid < st) red[tid] += red[tid + st];
    __syncthreads();
  }
  float inv = 1.0f / sqrtf(red[0] * (1.0f / H) + 1e-12f);
  for (int i = tid; i < H; i += 256) {
    float o = (buf[i] - mean) * inv * g[i] + bta[i];
    xhl[(size_t)row * H + i] = packhl(o);
  }
}

// x = LayerNorm(unpack(xhl) + y) * g + b ; write packed hi/lo back to xhl
__global__ __launch_bounds__(256) void add_ln_kernel(uint* __restrict__ xhl,
                                                     const float* __restrict__ y,
                                                     const float* __restrict__ g,
                                                     const float* __restrict__ bta) {
  __shared__ float buf[H];
  __shared__ float red[256];
  const size_t row = blockIdx.x;
  const int tid = threadIdx.x;
  float local = 0.f;
  for (int i = tid; i < H; i += 256) {
    float v = unpackhl(xhl[row * H + i]) + y[row * H + i];
    buf[i] = v;
    local += v;
  }
  red[tid] = local;
  __syncthreads();
  for (int st = 128; st > 0; st >>= 1) {
    if (tid < st) red[tid] += red[tid + st];
    __syncthreads();
  }
  float mean = red[0] * (1.0f / H);
  __syncthreads();
  float ls = 0.f;
  for (int i = tid; i < H; i += 256) {
    float d = buf[i] - mean;
    ls += d * d;
  }
  red[tid] = ls;
  __syncthreads();
  for (int st = 128; st > 0; st >>= 1) {
    if (tid < st) red[tid] += red[tid + st];
    __syncthreads();
  }
  float inv = 1.0f / sqrtf(red[0] * (1.0f / H) + 1e-12f);
  for (int i = tid; i < H; i += 256) {
    float o = (buf[i] - mean) * inv * g[i] + bta[i];
    xhl[row * H + i] = packhl(o);
  }
}

__global__ __launch_bounds__(256) void fc_kernel(const uint* __restrict__ xhl,
                                                 const float* __restrict__ w,
                                                 const float* __restrict__ bias,
                                                 float* __restrict__ logits) {
  __shared__ float xs[H];
  const size_t row = blockIdx.x;
  const int tid = threadIdx.x;
  for (int i = tid; i < H; i += 256) xs[i] = unpackhl(xhl[row * H + i]);
  __syncthreads();
  const int j = tid >> 4, l = tid & 15;
  if (j < T) {
    float s = 0.f;
    for (int k = l; k < H; k += 16) s += xs[k] * w[(size_t)k * T + j];
#pragma unroll
    for (int d = 8; d > 0; d >>= 1) s += __shfl_down(s, d, 16);
    if (l == 0) logits[row * T + j] = s + bias[j];
  }
}

__global__ __launch_bounds__(64) void crf_llh_kernel(const float* __restrict__ em,
                                                     const int* __restrict__ label,
                                                     const int* __restrict__ mask,
                                                     const float* __restrict__ start,
                                                     const float* __restrict__ endw,
                                                     const float* __restrict__ trans,
                                                     float* __restrict__ llh) {
  const int b = blockIdx.x;
  const int c = threadIdx.x;
  __shared__ float alpha[T];
  __shared__ float tr[T][T];
  for (int i = c; i < T * T; i += 64) tr[i / T][i % T] = trans[i];
  if (c < T) alpha[c] = start[c] + em[(size_t)b * S * T + c];
  __syncthreads();
  for (int s = 1; s < S; ++s) {
    float a = 0.f;
    if (c < T) {
      float mx = -1e30f;
      for (int p = 0; p < T; ++p) mx = fmaxf(mx, alpha[p] + tr[p][c]);
      float sum = 0.f;
      for (int p = 0; p < T; ++p) sum += expf(alpha[p] + tr[p][c] - mx);
      a = mx + logf(sum) + em[((size_t)b * S + s) * T + c];
    }
    __syncthreads();
    if (c < T) {
      float m = (float)mask[b * S + s];
      alpha[c] = (m > 0.f) ? a : alpha[c];
    }
    __syncthreads();
  }
  if (c == 0) {
    float mx = -1e30f;
    for (int p = 0; p < T; ++p) mx = fmaxf(mx, alpha[p] + endw[p]);
    float sum = 0.f;
    for (int p = 0; p < T; ++p) sum += expf(alpha[p] + endw[p] - mx);
    float denom = mx + logf(sum);

    int t0 = label[b * S];
    float score = start[t0] + em[(size_t)b * S * T + t0];
    int prev = t0;
    for (int s = 1; s < S; ++s) {
      int tc = label[b * S + s];
      float m = (float)mask[b * S + s];
      score += (tr[prev][tc] + em[((size_t)b * S + s) * T + tc]) * m;
      prev = tc;
    }
    int msum = 0;
    for (int s = 0; s < S; ++s) msum += mask[b * S + s];
    score += endw[label[b * S + (msum - 1)]];
    llh[b] = score - denom;
  }
}

__global__ __launch_bounds__(256) void loss_kernel(const float* __restrict__ llh,
                                                   float* __restrict__ out) {
  __shared__ float red[256];
  const int tid = threadIdx.x;
  red[tid] = llh[tid];  // B == 256
  __syncthreads();
  for (int st = 128; st > 0; st >>= 1) {
    if (tid < st) red[tid] += red[tid + st];
    __syncthreads();
  }
  if (tid == 0) out[BS] = -red[0] * (1.0f / B);
}

__global__ __launch_bounds__(64) void viterbi_kernel(const float* __restrict__ em,
                                                     const int* __restrict__ mask,
                                                     const float* __restrict__ start,
                                                     const float* __restrict__ endw,
                                                     const float* __restrict__ trans,
                                                     float* __restrict__ pred) {
  const int b = blockIdx.x;
  const int c = threadIdx.x;
  __shared__ float sc[T];
  __shared__ float tr[T][T];
  __shared__ int hist[S - 1][T];
  for (int i = c; i < T * T; i += 64) tr[i / T][i % T] = trans[i];
  if (c < T) sc[c] = start[c] + em[(size_t)b * S * T + c];
  __syncthreads();
  for (int s = 1; s < S; ++s) {
    float bestv = -1e30f;
    int bestp = 0;
    if (c < T) {
      for (int p = 0; p < T; ++p) {
        float v = sc[p] + tr[p][c];
        if (v > bestv) { bestv = v; bestp = p; }
      }
      hist[s - 1][c] = bestp;
    }
    __syncthreads();
    if (c < T) {
      float m = (float)mask[b * S + s];
      sc[c] = (m > 0.f) ? (bestv + em[((size_t)b * S + s) * T + c]) : sc[c];
    }
    __syncthreads();
  }
  if (c == 0) {
    float bv = -1e30f;
    int last = 0;
    for (int p = 0; p < T; ++p) {
      float v = sc[p] + endw[p];
      if (v > bv) { bv = v; last = p; }
    }
    pred[b * S + (S - 1)] = (float)last;
    int t = last;
    for (int hs = S - 2; hs >= 0; --hs) {
      if (mask[b * S + hs + 1] > 0) t = hist[hs][t];
      pred[b * S + hs] = (float)t;
    }
  }
}

}  // namespace

extern "C" void kernel_launch(void* const* d_in, const int* in_sizes, int n_in,
                              void* d_out, int out_size, void* d_ws, size_t ws_size,
                              hipStream_t stream) {
  (void)in_sizes; (void)n_in; (void)out_size; (void)ws_size;
  const int* input_ids = (const int*)d_in[0];
  const int* attn_mask = (const int*)d_in[1];
  const int* label = (const int*)d_in[2];
  const float* word_emb = (const float*)d_in[3];
  const float* pos_emb = (const float*)d_in[4];
  const float* tok_emb = (const float*)d_in[5];
  const float* eg = (const float*)d_in[6];
  const float* ebt = (const float*)d_in[7];
  const float* Wqkv = (const float*)d_in[8];
  const float* bqkv = (const float*)d_in[9];
  const float* Wo = (const float*)d_in[10];
  const float* bo = (const float*)d_in[11];
  const float* ln1g = (const float*)d_in[12];
  const float* ln1b = (const float*)d_in[13];
  const float* W1 = (const float*)d_in[14];
  const float* b1 = (const float*)d_in[15];
  const float* W2 = (const float*)d_in[16];
  const float* b2 = (const float*)d_in[17];
  const float* ln2g = (const float*)d_in[18];
  const float* ln2b = (const float*)d_in[19];
  const float* fc_w = (const float*)d_in[20];
  const float* fc_b = (const float*)d_in[21];
  const float* crf_start = (const float*)d_in[22];
  const float* crf_end = (const float*)d_in[23];
  const float* crf_trans = (const float*)d_in[24];
  float* out = (float*)d_out;

  // ---- workspace layout (~281 MB, proven footprint) ----
  char* p = (char*)d_ws;
  uint* xhl = (uint*)p;        p += (size_t)BS * H * 4;          // packed residual
  float* tmpA = (float*)p;     p += (size_t)BS * H * 4;          // fp32 atomic dst
  ushort* wQ = (ushort*)p;     p += (size_t)3 * H * 2 * H * 2;   // [2304][1536] bf16
  ushort* wO = (ushort*)p;     p += (size_t)H * 2 * H * 2;       // [768][1536]
  ushort* wF1 = (ushort*)p;    p += (size_t)F * 2 * H * 2;       // [3072][1536]
  ushort* wF2 = (ushort*)p;    p += (size_t)H * 2 * F * 2;       // [768][6144]
  uint* big = (uint*)p;        p += (size_t)BS * 3 * H * 4;      // 151 MB
  float* logits = (float*)p;   p += (size_t)BS * T * 4;
  float* llh = (float*)p;      p += (size_t)B * 4;
  uint* qkvU = big;   // [BS][3H] packed; attn out lands in Q-slot cols
  uint* hU = big;     // [RC][F] packed (FFN phase, per chunk)

  embed_ln_kernel<<<BS, 256, 0, stream>>>(input_ids, word_emb, pos_emb, tok_emb, eg, ebt, xhl);

  for (int l = 0; l < L; ++l) {
    const float* wqkv_l = Wqkv + (size_t)l * H * 3 * H;
    const float* bqkv_l = bqkv + (size_t)l * 3 * H;
    const float* wo_l = Wo + (size_t)l * H * H;
    const float* bo_l = bo + (size_t)l * H;
    const float* g1 = ln1g + (size_t)l * H;
    const float* be1 = ln1b + (size_t)l * H;
    const float* w1_l = W1 + (size_t)l * H * F;
    const float* b1_l = b1 + (size_t)l * F;
    const float* w2_l = W2 + (size_t)l * F * H;
    const float* b2_l = b2 + (size_t)l * H;
    const float* g2 = ln2g + (size_t)l * H;
    const float* be2 = ln2b + (size_t)l * H;

    convert_w_t<<<dim3(3 * H / 32, H / 32), 256, 0, stream>>>(wqkv_l, wQ, H, 3 * H);
    convert_w_t<<<dim3(H / 32, H / 32), 256, 0, stream>>>(wo_l, wO, H, H);
    convert_w_t<<<dim3(F / 32, H / 32), 256, 0, stream>>>(w1_l, wF1, H, F);
    convert_w_t<<<dim3(H / 32, F / 32), 256, 0, stream>>>(w2_l, wF2, F, H);

    // ---- attention block ----
    // QKV: [BS,H] @ [H,3H] -> qkvU packed.  grid 9x128 = 1152
    gemm_mfma<2><<<dim3(3 * H / 256, BS / 128, 1), 512, 0, stream>>>(
        xhl, wQ, bqkv_l, nullptr, qkvU, H, 2 * H, 3 * H, H / 32);
    attn_kernel<<<B * NH, 256, 0, stream>>>(qkvU, attn_mask);
    // Wo: [BS,H(Q-slot)] @ [H,H] -> tmpA (atomic, z=2).  grid 3x128x2 = 768
    fill_bias_kernel<<<BS * H / 4 / 256, 256, 0, stream>>>(tmpA, bo_l);
    gemm_mfma<3><<<dim3(H / 256, BS / 128, 2), 512, 0, stream>>>(
        qkvU, wO, nullptr, tmpA, nullptr, 3 * H, 2 * H, H, H / 64);
    add_ln_kernel<<<BS, 256, 0, stream>>>(xhl, tmpA, g1, be1);

    // ---- FFN block ----
    fill_bias_kernel<<<BS * H / 4 / 256, 256, 0, stream>>>(tmpA, b2_l);
    for (int ch = 0; ch < NCH; ++ch) {
      // FFN1: [RC,H] @ [H,F] -> hU (gelu, packed).  grid 12x64 = 768
      gemm_mfma<1><<<dim3(F / 256, RC / 128, 1), 512, 0, stream>>>(
          xhl + (size_t)ch * RC * H, wF1, b1_l, nullptr, hU, H, 2 * H, F, H / 32);
      // FFN2: [RC,F] @ [F,H] -> tmpA (atomic, z=4).  grid 3x64x4 = 768
      gemm_mfma<3><<<dim3(H / 256, RC / 128, 4), 512, 0, stream>>>(
          hU, wF2, nullptr, tmpA + (size_t)ch * RC * H, nullptr, F, 2 * F, H, F / 128);
    }
    add_ln_kernel<<<BS, 256, 0, stream>>>(xhl, tmpA, g2, be2);
  }

  fc_kernel<<<BS, 256, 0, stream>>>(xhl, fc_w, fc_b, logits);
  crf_llh_kernel<<<B, 64, 0, stream>>>(logits, label, attn_mask, crf_start, crf_end, crf_trans, llh);
  loss_kernel<<<1, 256, 0, stream>>>(llh, out);
  viterbi_kernel<<<B, 64, 0, stream>>>(logits, attn_mask, crf_start, crf_end, crf_trans, out);
}

// Round 6
// 11613.469 us; speedup vs baseline: 1.4152x; 1.2503x over previous
//
#include <hip/hip_runtime.h>
#include <hip/hip_bf16.h>
#include <math.h>

namespace {

constexpr int B = 256, S = 64, H = 768, L = 12, NH = 12, F = 3072, T = 11;
constexpr int BS = B * S;   // 16384 rows
constexpr int RC = 8192;    // rows per FFN chunk
constexpr int NCH = BS / RC;

typedef __attribute__((ext_vector_type(8))) short short8;
typedef __attribute__((ext_vector_type(4))) float f32x4;

__device__ __forceinline__ float gelu_tanh(float v) {
  float u = 0.7978845608028654f * (v + 0.044715f * v * v * v);
  u = fminf(fmaxf(u, -10.f), 10.f);
  float t = __expf(2.f * u);
  return 0.5f * v * (1.0f + (t - 1.f) / (t + 1.f));
}

// RNE float->bf16
__device__ __forceinline__ ushort f2bf(float v) {
  union { float f; unsigned u; } c; c.f = v;
  unsigned r = (c.u + 0x7fffu + ((c.u >> 16) & 1u)) >> 16;
  return (ushort)r;
}
__device__ __forceinline__ float bf2f(ushort u) {
  union { unsigned u; float f; } c; c.u = ((unsigned)u) << 16;
  return c.f;
}
__device__ __forceinline__ uint packhl(float v) {
  ushort hi = f2bf(v);
  ushort lo = f2bf(v - bf2f(hi));
  return (uint)hi | ((uint)lo << 16);
}
__device__ __forceinline__ float unpackhl(uint u) {
  union { unsigned u; float f; } a, b;
  a.u = u << 16;
  b.u = u & 0xffff0000u;
  return a.f + b.f;
}

__device__ __forceinline__ uint prm(uint a, uint b, uint s) {
#if __has_builtin(__builtin_amdgcn_perm)
  return __builtin_amdgcn_perm(a, b, s);
#else
  uint r = 0;
  for (int i = 0; i < 4; ++i) {
    uint sel = (s >> (8 * i)) & 0xff;
    uint byte = sel < 4 ? (b >> (8 * sel)) & 0xff : (a >> (8 * (sel - 4))) & 0xff;
    r |= byte << (8 * i);
  }
  return r;
#endif
}

union S8U { uint u[4]; short8 s; };

// v0 = packed elems k..k+3, v1 = k+4..k+7 -> hi-frag / lo-frag short8
__device__ __forceinline__ void unpack_frag(uint4 v0, uint4 v1, short8& hi, short8& lo) {
  S8U h, l;
  h.u[0] = prm(v0.y, v0.x, 0x05040100u);
  l.u[0] = prm(v0.y, v0.x, 0x07060302u);
  h.u[1] = prm(v0.w, v0.z, 0x05040100u);
  l.u[1] = prm(v0.w, v0.z, 0x07060302u);
  h.u[2] = prm(v1.y, v1.x, 0x05040100u);
  l.u[2] = prm(v1.y, v1.x, 0x07060302u);
  h.u[3] = prm(v1.w, v1.z, 0x05040100u);
  l.u[3] = prm(v1.w, v1.z, 0x07060302u);
  hi = h.s;
  lo = l.s;
}

#define GLOAD_LDS16(gptr, ldsptr)                                                        \
  __builtin_amdgcn_global_load_lds((const __attribute__((address_space(1))) void*)(gptr), \
                                   (__attribute__((address_space(3))) void*)(ldsptr), 16, 0, 0)

// ============ 128x128 4-wave, 2 blocks/CU, 4-phase GEMM ============
// C = (Ahi+Alo)[M,K] @ (Bhi+Blo)[N,K]^T via 3 bf16 MFMA products, fp32 accum.
// A: packed u32 (hi | lo<<16), row stride lda (u32 elems).
// B: planar block-interleaved bf16 [N][2K] (k-block j: 32 hi then 32 lo), stride ldb2.
// MODE 1: gelu(v+bias) -> packed u32. MODE 2: v+bias -> packed u32.
// MODE 3: fp32 partial store (deterministic split-K): dst = outF + bz*zStrideF + row*ldcF + col.
template <int MODE>
__global__ __launch_bounds__(256, 2) void gemm_mfma(const uint* __restrict__ A,
                                                    const ushort* __restrict__ Bw,
                                                    const float* __restrict__ bias,
                                                    float* __restrict__ outF,
                                                    uint* __restrict__ outU,
                                                    int lda, int ldb2, int ldc,
                                                    int ldcF, int zStrideF, int ktiles) {
  __shared__ uint sA[2][128 * 32];     // [buf][row][32 u32]   128B rows (32KB)
  __shared__ ushort sB[2][128 * 64];   // [buf][row][64 bf16]  128B rows (32KB)
  const int tid = threadIdx.x;
  const int w = tid >> 6;       // 0..3
  const int lane = tid & 63;
  const int wm = w >> 1;        // 0..1
  const int wn = w & 1;         // 0..1

  // bijective XCD swizzle over the whole grid (all totals % 8 == 0)
  const int gx = gridDim.x, gy = gridDim.y;
  const int flat = ((int)blockIdx.z * gy + blockIdx.y) * gx + blockIdx.x;
  const int q8 = (gx * gy * (int)gridDim.z) >> 3;
  const int swz = (flat & 7) * q8 + (flat >> 3);
  const int bx = swz % gx;
  const int by = (swz / gx) % gy;
  const int bz = swz / (gx * gy);
  const int bm = by * 128;
  const int bn = bx * 128;
  const int kA0 = bz * ktiles * 32;   // u32 elements
  const int kB0 = bz * ktiles * 64;   // ushort elements

  // staging: per 8-row/1KB DMA chunk, lane l -> row +(l>>3), phys 16B-block l&7
  // sourced from logical block (l&7)^(l>>3)  (XOR swizzle, matched on read side)
  const int srow = lane >> 3;
  const int sblk = (lane & 7) ^ srow;
  const uint* Ab = A + (size_t)(bm + w * 32 + srow) * lda + kA0 + sblk * 4;
  const ushort* Bb = Bw + (size_t)(bn + w * 32 + srow) * ldb2 + kB0 + sblk * 8;

#define STAGE(buf, tk)                                                            \
  do {                                                                            \
    _Pragma("unroll") for (int i_ = 0; i_ < 4; ++i_) {                            \
      GLOAD_LDS16(Ab + (size_t)(tk) * 32 + (size_t)(i_ * 8) * lda,                \
                  &sA[buf][(w * 32 + i_ * 8) * 32]);                              \
      GLOAD_LDS16(Bb + (size_t)(tk) * 64 + (size_t)(i_ * 8) * ldb2,               \
                  &sB[buf][(w * 32 + i_ * 8) * 64]);                              \
    }                                                                             \
  } while (0)

  // fragment read constants (16x16x32: row = lane&15, k = 8*(lane>>4)+0..7)
  const int fr = lane & 15;
  const int s7 = fr & 7;
  const int jb = lane >> 4;                 // 0..3
  const int p0 = ((jb << 1) ^ s7) << 2;     // A swizzled u32 offsets
  const int p1 = (((jb << 1) ^ s7) ^ 1) << 2;
  const int bhOff = (jb ^ s7) << 3;         // B hi: logical blocks 0..3
  const int blOff = ((4 + jb) ^ s7) << 3;   // B lo: logical blocks 4..7

  f32x4 acc[4][4] = {};
  const int NT = ktiles;

  STAGE(0, 0);
  asm volatile("s_waitcnt vmcnt(0)" ::: "memory");
  __builtin_amdgcn_s_barrier();

  for (int t = 0; t < NT; ++t) {
    const int cur = t & 1;
    if (t + 1 < NT) STAGE(cur ^ 1, t + 1);  // 8 DMAs/wave, drained at phase 4

    // phase 1 payload: all A fragments + B ni=0
    short8 ah[4], al[4];
#pragma unroll
    for (int mi = 0; mi < 4; ++mi) {
      const uint* baseA = &sA[cur][(wm * 64 + mi * 16 + fr) * 32];
      uint4 v0 = *(const uint4*)(baseA + p0);
      uint4 v1 = *(const uint4*)(baseA + p1);
      unpack_frag(v0, v1, ah[mi], al[mi]);
    }
#pragma unroll
    for (int ni = 0; ni < 4; ++ni) {  // 4 phases, one per ni
      const ushort* baseB = &sB[cur][(wn * 64 + ni * 16 + fr) * 64];
      short8 bh = *(const short8*)(baseB + bhOff);
      short8 bl = *(const short8*)(baseB + blOff);
      __builtin_amdgcn_s_setprio(1);
#pragma unroll
      for (int mi = 0; mi < 4; ++mi) {
        acc[mi][ni] = __builtin_amdgcn_mfma_f32_16x16x32_bf16(ah[mi], bh, acc[mi][ni], 0, 0, 0);
        acc[mi][ni] = __builtin_amdgcn_mfma_f32_16x16x32_bf16(ah[mi], bl, acc[mi][ni], 0, 0, 0);
        acc[mi][ni] = __builtin_amdgcn_mfma_f32_16x16x32_bf16(al[mi], bh, acc[mi][ni], 0, 0, 0);
      }
      __builtin_amdgcn_s_setprio(0);
      if (ni == 3) asm volatile("s_waitcnt vmcnt(0)" ::: "memory");  // own stages landed
      __builtin_amdgcn_s_barrier();  // all waves' stages landed -> next tile readable
    }
  }
#undef STAGE

  const int erow = jb << 2;  // C/D: col=lane&15, row=(lane>>4)*4+e
#pragma unroll
  for (int ni = 0; ni < 4; ++ni) {
    const int col = bn + wn * 64 + ni * 16 + fr;
    const float bv = (MODE == 3) ? 0.f : bias[col];
#pragma unroll
    for (int mi = 0; mi < 4; ++mi) {
#pragma unroll
      for (int e = 0; e < 4; ++e) {
        const int row = bm + wm * 64 + mi * 16 + erow + e;
        float v = acc[mi][ni][e] + bv;
        if (MODE == 1) {
          outU[(size_t)row * ldc + col] = packhl(gelu_tanh(v));
        } else if (MODE == 2) {
          outU[(size_t)row * ldc + col] = packhl(v);
        } else {
          outF[(size_t)bz * zStrideF + (size_t)row * ldcF + col] = v;
        }
      }
    }
  }
}

// W[K][N] fp32 -> planar block-interleaved bf16 [N][2K]
__global__ __launch_bounds__(256) void convert_w_t(const float* __restrict__ W,
                                                   ushort* __restrict__ WI, int K, int N) {
  __shared__ float tile[32][33];
  const int kb = blockIdx.y * 32, nb = blockIdx.x * 32;
  const int tr = threadIdx.x >> 5;
  const int tc = threadIdx.x & 31;
#pragma unroll
  for (int p = 0; p < 4; ++p) {
    int r = tr + p * 8;
    tile[r][tc] = W[(size_t)(kb + r) * N + nb + tc];
  }
  __syncthreads();
  const int kblk = kb >> 5;
#pragma unroll
  for (int p = 0; p < 4; ++p) {
    int n = tr + p * 8;
    float v = tile[tc][n];
    ushort hi = f2bf(v);
    ushort lo = f2bf(v - bf2f(hi));
    size_t o = (size_t)(nb + n) * (2 * K) + (size_t)kblk * 64 + tc;
    WI[o] = hi;
    WI[o + 32] = lo;
  }
}

// One block per (batch, head). qkv packed u32 [row][3H]; writes output
// IN PLACE into the Q-slot columns (block reads all its Q/K/V to LDS first).
__global__ __launch_bounds__(256) void attn_kernel(uint* __restrict__ qkv,
                                                   const int* __restrict__ mask) {
  __shared__ float smem[64 * 64 + 64 * 66 + 64 * 64];  // Qs | KsT | Vs ; Ps aliases
  float (*Qs)[64] = (float (*)[64])smem;
  float (*KsT)[66] = (float (*)[66])(smem + 64 * 64);
  float (*Vs)[64] = (float (*)[64])(smem + 64 * 64 + 64 * 66);
  float (*Ps)[65] = (float (*)[65])smem;

  const int bl = blockIdx.x / NH;
  const int hh = blockIdx.x % NH;
  const int tid = threadIdx.x;
  const int lane = tid & 63;
  const int w = tid >> 6;

  for (int i = 0; i < 16; ++i) {
    int idx = tid + i * 256;
    int r = idx >> 6, d = idx & 63;
    size_t base = (size_t)(bl * 64 + r) * (3 * H) + hh * 64 + d;
    Qs[r][d] = unpackhl(qkv[base]);
    KsT[d][r] = unpackhl(qkv[base + H]);
    Vs[r][d] = unpackhl(qkv[base + 2 * H]);
  }
  __syncthreads();

  float sc[16];
#pragma unroll
  for (int i = 0; i < 16; ++i) sc[i] = 0.f;
  for (int d = 0; d < 64; ++d) {
    float kv = KsT[d][lane];
#pragma unroll
    for (int i = 0; i < 16; ++i) sc[i] += Qs[w + 4 * i][d] * kv;
  }
  __syncthreads();
  float biask = (1.0f - (float)mask[bl * S + lane]) * -1e9f;
#pragma unroll
  for (int i = 0; i < 16; ++i) Ps[w + 4 * i][lane] = sc[i] * 0.125f + biask;
  __syncthreads();

  if (tid < 64) {
    int qr = tid;
    float mx = -1e30f;
    for (int k = 0; k < 64; ++k) mx = fmaxf(mx, Ps[qr][k]);
    float sum = 0.f;
    for (int k = 0; k < 64; ++k) {
      float e = expf(Ps[qr][k] - mx);
      Ps[qr][k] = e;
      sum += e;
    }
    float inv = 1.0f / sum;
    for (int k = 0; k < 64; ++k) Ps[qr][k] *= inv;
  }
  __syncthreads();

  float o[16];
#pragma unroll
  for (int i = 0; i < 16; ++i) o[i] = 0.f;
  for (int k = 0; k < 64; ++k) {
    float vv = Vs[k][lane];
#pragma unroll
    for (int i = 0; i < 16; ++i) o[i] += Ps[w + 4 * i][k] * vv;
  }
#pragma unroll
  for (int i = 0; i < 16; ++i) {
    int qr = w + 4 * i;
    qkv[(size_t)(bl * 64 + qr) * (3 * H) + hh * 64 + lane] = packhl(o[i]);
  }
}

__global__ __launch_bounds__(256) void embed_ln_kernel(const int* __restrict__ ids,
                                                       const float* __restrict__ we,
                                                       const float* __restrict__ pe,
                                                       const float* __restrict__ te,
                                                       const float* __restrict__ g,
                                                       const float* __restrict__ bta,
                                                       uint* __restrict__ xhl) {
  __shared__ float buf[H];
  __shared__ float red[256];
  const int row = blockIdx.x;
  const int s = row % S;
  const int tid = threadIdx.x;
  const int id = ids[row];
  float local = 0.f;
  for (int i = tid; i < H; i += 256) {
    float v = we[(size_t)id * H + i] + pe[(size_t)s * H + i] + te[i];
    buf[i] = v;
    local += v;
  }
  red[tid] = local;
  __syncthreads();
  for (int st = 128; st > 0; st >>= 1) {
    if (tid < st) red[tid] += red[tid + st];
    __syncthreads();
  }
  float mean = red[0] * (1.0f / H);
  __syncthreads();
  float ls = 0.f;
  for (int i = tid; i < H; i += 256) {
    float d = buf[i] - mean;
    ls += d * d;
  }
  red[tid] = ls;
  __syncthreads();
  for (int st = 128; st > 0; st >>= 1) {
    if (tid < st) red[tid] += red[tid + st];
    __syncthreads();
  }
  float inv = 1.0f / sqrtf(red[0] * (1.0f / H) + 1e-12f);
  for (int i = tid; i < H; i += 256) {
    float o = (buf[i] - mean) * inv * g[i] + bta[i];
    xhl[(size_t)row * H + i] = packhl(o);
  }
}

// xhl = pack(LayerNorm(unpack(xhl) + p0 + p1 + bias) * g + b)   (deterministic z-sum)
__global__ __launch_bounds__(256) void add_ln_kernel(uint* __restrict__ xhl,
                                                     const float* __restrict__ pz0,
                                                     const float* __restrict__ pz1,
                                                     int prs,
                                                     const float* __restrict__ biasv,
                                                     const float* __restrict__ g,
                                                     const float* __restrict__ bta) {
  __shared__ float buf[H];
  __shared__ float red[256];
  const size_t row = blockIdx.x;
  const int tid = threadIdx.x;
  float local = 0.f;
  for (int i = tid; i < H; i += 256) {
    float v = unpackhl(xhl[row * H + i]) + ((pz0[row * (size_t)prs + i] + pz1[row * (size_t)prs + i]) + biasv[i]);
    buf[i] = v;
    local += v;
  }
  red[tid] = local;
  __syncthreads();
  for (int st = 128; st > 0; st >>= 1) {
    if (tid < st) red[tid] += red[tid + st];
    __syncthreads();
  }
  float mean = red[0] * (1.0f / H);
  __syncthreads();
  float ls = 0.f;
  for (int i = tid; i < H; i += 256) {
    float d = buf[i] - mean;
    ls += d * d;
  }
  red[tid] = ls;
  __syncthreads();
  for (int st = 128; st > 0; st >>= 1) {
    if (tid < st) red[tid] += red[tid + st];
    __syncthreads();
  }
  float inv = 1.0f / sqrtf(red[0] * (1.0f / H) + 1e-12f);
  for (int i = tid; i < H; i += 256) {
    float o = (buf[i] - mean) * inv * g[i] + bta[i];
    xhl[row * H + i] = packhl(o);
  }
}

__global__ __launch_bounds__(256) void fc_kernel(const uint* __restrict__ xhl,
                                                 const float* __restrict__ w,
                                                 const float* __restrict__ bias,
                                                 float* __restrict__ logits) {
  __shared__ float xs[H];
  const size_t row = blockIdx.x;
  const int tid = threadIdx.x;
  for (int i = tid; i < H; i += 256) xs[i] = unpackhl(xhl[row * H + i]);
  __syncthreads();
  const int j = tid >> 4, l = tid & 15;
  if (j < T) {
    float s = 0.f;
    for (int k = l; k < H; k += 16) s += xs[k] * w[(size_t)k * T + j];
#pragma unroll
    for (int d = 8; d > 0; d >>= 1) s += __shfl_down(s, d, 16);
    if (l == 0) logits[row * T + j] = s + bias[j];
  }
}

__global__ __launch_bounds__(64) void crf_llh_kernel(const float* __restrict__ em,
                                                     const int* __restrict__ label,
                                                     const int* __restrict__ mask,
                                                     const float* __restrict__ start,
                                                     const float* __restrict__ endw,
                                                     const float* __restrict__ trans,
                                                     float* __restrict__ llh) {
  const int b = blockIdx.x;
  const int c = threadIdx.x;
  __shared__ float alpha[T];
  __shared__ float tr[T][T];
  for (int i = c; i < T * T; i += 64) tr[i / T][i % T] = trans[i];
  if (c < T) alpha[c] = start[c] + em[(size_t)b * S * T + c];
  __syncthreads();
  for (int s = 1; s < S; ++s) {
    float a = 0.f;
    if (c < T) {
      float mx = -1e30f;
      for (int p = 0; p < T; ++p) mx = fmaxf(mx, alpha[p] + tr[p][c]);
      float sum = 0.f;
      for (int p = 0; p < T; ++p) sum += expf(alpha[p] + tr[p][c] - mx);
      a = mx + logf(sum) + em[((size_t)b * S + s) * T + c];
    }
    __syncthreads();
    if (c < T) {
      float m = (float)mask[b * S + s];
      alpha[c] = (m > 0.f) ? a : alpha[c];
    }
    __syncthreads();
  }
  if (c == 0) {
    float mx = -1e30f;
    for (int p = 0; p < T; ++p) mx = fmaxf(mx, alpha[p] + endw[p]);
    float sum = 0.f;
    for (int p = 0; p < T; ++p) sum += expf(alpha[p] + endw[p] - mx);
    float denom = mx + logf(sum);

    int t0 = label[b * S];
    float score = start[t0] + em[(size_t)b * S * T + t0];
    int prev = t0;
    for (int s = 1; s < S; ++s) {
      int tc = label[b * S + s];
      float m = (float)mask[b * S + s];
      score += (tr[prev][tc] + em[((size_t)b * S + s) * T + tc]) * m;
      prev = tc;
    }
    int msum = 0;
    for (int s = 0; s < S; ++s) msum += mask[b * S + s];
    score += endw[label[b * S + (msum - 1)]];
    llh[b] = score - denom;
  }
}

__global__ __launch_bounds__(256) void loss_kernel(const float* __restrict__ llh,
                                                   float* __restrict__ out) {
  __shared__ float red[256];
  const int tid = threadIdx.x;
  red[tid] = llh[tid];  // B == 256
  __syncthreads();
  for (int st = 128; st > 0; st >>= 1) {
    if (tid < st) red[tid] += red[tid + st];
    __syncthreads();
  }
  if (tid == 0) out[BS] = -red[0] * (1.0f / B);
}

__global__ __launch_bounds__(64) void viterbi_kernel(const float* __restrict__ em,
                                                     const int* __restrict__ mask,
                                                     const float* __restrict__ start,
                                                     const float* __restrict__ endw,
                                                     const float* __restrict__ trans,
                                                     float* __restrict__ pred) {
  const int b = blockIdx.x;
  const int c = threadIdx.x;
  __shared__ float sc[T];
  __shared__ float tr[T][T];
  __shared__ int hist[S - 1][T];
  for (int i = c; i < T * T; i += 64) tr[i / T][i % T] = trans[i];
  if (c < T) sc[c] = start[c] + em[(size_t)b * S * T + c];
  __syncthreads();
  for (int s = 1; s < S; ++s) {
    float bestv = -1e30f;
    int bestp = 0;
    if (c < T) {
      for (int p = 0; p < T; ++p) {
        float v = sc[p] + tr[p][c];
        if (v > bestv) { bestv = v; bestp = p; }
      }
      hist[s - 1][c] = bestp;
    }
    __syncthreads();
    if (c < T) {
      float m = (float)mask[b * S + s];
      sc[c] = (m > 0.f) ? (bestv + em[((size_t)b * S + s) * T + c]) : sc[c];
    }
    __syncthreads();
  }
  if (c == 0) {
    float bv = -1e30f;
    int last = 0;
    for (int p = 0; p < T; ++p) {
      float v = sc[p] + endw[p];
      if (v > bv) { bv = v; last = p; }
    }
    pred[b * S + (S - 1)] = (float)last;
    int t = last;
    for (int hs = S - 2; hs >= 0; --hs) {
      if (mask[b * S + hs + 1] > 0) t = hist[hs][t];
      pred[b * S + hs] = (float)t;
    }
  }
}

}  // namespace

extern "C" void kernel_launch(void* const* d_in, const int* in_sizes, int n_in,
                              void* d_out, int out_size, void* d_ws, size_t ws_size,
                              hipStream_t stream) {
  (void)in_sizes; (void)n_in; (void)out_size; (void)ws_size;
  const int* input_ids = (const int*)d_in[0];
  const int* attn_mask = (const int*)d_in[1];
  const int* label = (const int*)d_in[2];
  const float* word_emb = (const float*)d_in[3];
  const float* pos_emb = (const float*)d_in[4];
  const float* tok_emb = (const float*)d_in[5];
  const float* eg = (const float*)d_in[6];
  const float* ebt = (const float*)d_in[7];
  const float* Wqkv = (const float*)d_in[8];
  const float* bqkv = (const float*)d_in[9];
  const float* Wo = (const float*)d_in[10];
  const float* bo = (const float*)d_in[11];
  const float* ln1g = (const float*)d_in[12];
  const float* ln1b = (const float*)d_in[13];
  const float* W1 = (const float*)d_in[14];
  const float* b1 = (const float*)d_in[15];
  const float* W2 = (const float*)d_in[16];
  const float* b2 = (const float*)d_in[17];
  const float* ln2g = (const float*)d_in[18];
  const float* ln2b = (const float*)d_in[19];
  const float* fc_w = (const float*)d_in[20];
  const float* fc_b = (const float*)d_in[21];
  const float* crf_start = (const float*)d_in[22];
  const float* crf_end = (const float*)d_in[23];
  const float* crf_trans = (const float*)d_in[24];
  float* out = (float*)d_out;

  // ---- workspace layout (~231 MB, under the proven 281 MB footprint) ----
  char* p = (char*)d_ws;
  uint* xhl = (uint*)p;        p += (size_t)BS * H * 4;          // packed residual
  ushort* wQ = (ushort*)p;     p += (size_t)3 * H * 2 * H * 2;   // [2304][1536] bf16 planar
  ushort* wO = (ushort*)p;     p += (size_t)H * 2 * H * 2;       // [768][1536]
  ushort* wF1 = (ushort*)p;    p += (size_t)F * 2 * H * 2;       // [3072][1536]
  ushort* wF2 = (ushort*)p;    p += (size_t)H * 2 * F * 2;       // [768][6144]
  uint* big = (uint*)p;        p += (size_t)BS * 3 * H * 4;      // 151 MB
  float* logits = (float*)p;   p += (size_t)BS * T * 4;
  float* llh = (float*)p;      p += (size_t)B * 4;
  uint* qkvU = big;                         // [BS][3H] packed; attn out -> Q-slot
  uint* hU = big;                           // [RC][F] packed (FFN phase)
  float* pf = (float*)(big + (size_t)RC * F);  // [2][RC][H] fp32 FFN2 partials (tail of big)
  float* qf = (float*)qkvU;                 // f32 view; Wo partials land in dead K/V slots

  embed_ln_kernel<<<BS, 256, 0, stream>>>(input_ids, word_emb, pos_emb, tok_emb, eg, ebt, xhl);

  for (int l = 0; l < L; ++l) {
    const float* wqkv_l = Wqkv + (size_t)l * H * 3 * H;
    const float* bqkv_l = bqkv + (size_t)l * 3 * H;
    const float* wo_l = Wo + (size_t)l * H * H;
    const float* bo_l = bo + (size_t)l * H;
    const float* g1 = ln1g + (size_t)l * H;
    const float* be1 = ln1b + (size_t)l * H;
    const float* w1_l = W1 + (size_t)l * H * F;
    const float* b1_l = b1 + (size_t)l * F;
    const float* w2_l = W2 + (size_t)l * F * H;
    const float* b2_l = b2 + (size_t)l * H;
    const float* g2 = ln2g + (size_t)l * H;
    const float* be2 = ln2b + (size_t)l * H;

    convert_w_t<<<dim3(3 * H / 32, H / 32), 256, 0, stream>>>(wqkv_l, wQ, H, 3 * H);
    convert_w_t<<<dim3(H / 32, H / 32), 256, 0, stream>>>(wo_l, wO, H, H);
    convert_w_t<<<dim3(F / 32, H / 32), 256, 0, stream>>>(w1_l, wF1, H, F);
    convert_w_t<<<dim3(H / 32, F / 32), 256, 0, stream>>>(w2_l, wF2, F, H);

    // ---- attention block ----
    // QKV: [BS,H] @ [H,3H] -> qkvU packed.  grid 18x128 = 2304 (9/CU)
    gemm_mfma<2><<<dim3(3 * H / 128, BS / 128, 1), 256, 0, stream>>>(
        xhl, wQ, bqkv_l, nullptr, qkvU, H, 2 * H, 3 * H, 0, 0, H / 32);
    attn_kernel<<<B * NH, 256, 0, stream>>>(qkvU, attn_mask);
    // Wo: [BS,H(Q-slot)] @ [H,H] -> fp32 partials into dead K/V slots (z=2, deterministic)
    // grid 6x128x2 = 1536 (6/CU)
    gemm_mfma<3><<<dim3(H / 128, BS / 128, 2), 256, 0, stream>>>(
        qkvU, wO, nullptr, qf + H, nullptr, 3 * H, 2 * H, 0, 3 * H, H, H / 64);
    add_ln_kernel<<<BS, 256, 0, stream>>>(xhl, qf + H, qf + 2 * H, 3 * H, bo_l, g1, be1);

    // ---- FFN block (chunked) ----
    for (int ch = 0; ch < NCH; ++ch) {
      // FFN1: [RC,H] @ [H,F] -> hU (gelu, packed).  grid 24x64 = 1536 (6/CU)
      gemm_mfma<1><<<dim3(F / 128, RC / 128, 1), 256, 0, stream>>>(
          xhl + (size_t)ch * RC * H, wF1, b1_l, nullptr, hU, H, 2 * H, F, 0, 0, H / 32);
      // FFN2: [RC,F] @ [F,H] -> fp32 partials pf (z=2).  grid 6x64x2 = 768 (3/CU)
      gemm_mfma<3><<<dim3(H / 128, RC / 128, 2), 256, 0, stream>>>(
          hU, wF2, nullptr, pf, nullptr, F, 2 * F, 0, H, RC * H, F / 64);
      add_ln_kernel<<<RC, 256, 0, stream>>>(xhl + (size_t)ch * RC * H, pf, pf + (size_t)RC * H,
                                            H, b2_l, g2, be2);
    }
  }

  fc_kernel<<<BS, 256, 0, stream>>>(xhl, fc_w, fc_b, logits);
  crf_llh_kernel<<<B, 64, 0, stream>>>(logits, label, attn_mask, crf_start, crf_end, crf_trans, llh);
  loss_kernel<<<1, 256, 0, stream>>>(llh, out);
  viterbi_kernel<<<B, 64, 0, stream>>>(logits, attn_mask, crf_start, crf_end, crf_trans, out);
}

// Round 7
// 11266.891 us; speedup vs baseline: 1.4588x; 1.0308x over previous
//
#include <hip/hip_runtime.h>
#include <hip/hip_bf16.h>
#include <math.h>

namespace {

constexpr int B = 256, S = 64, H = 768, L = 12, NH = 12, F = 3072, T = 11;
constexpr int BS = B * S;   // 16384 rows
constexpr int RC = 8192;    // rows per FFN chunk
constexpr int NCH = BS / RC;

typedef __attribute__((ext_vector_type(8))) short short8;
typedef __attribute__((ext_vector_type(4))) float f32x4;

__device__ __forceinline__ float gelu_tanh(float v) {
  float u = 0.7978845608028654f * (v + 0.044715f * v * v * v);
  u = fminf(fmaxf(u, -10.f), 10.f);
  float t = __expf(2.f * u);
  return 0.5f * v * (1.0f + (t - 1.f) / (t + 1.f));
}

// RNE float->bf16
__device__ __forceinline__ ushort f2bf(float v) {
  union { float f; unsigned u; } c; c.f = v;
  unsigned r = (c.u + 0x7fffu + ((c.u >> 16) & 1u)) >> 16;
  return (ushort)r;
}
__device__ __forceinline__ float bf2f(ushort u) {
  union { unsigned u; float f; } c; c.u = ((unsigned)u) << 16;
  return c.f;
}
__device__ __forceinline__ void split2(float v, ushort& hi, ushort& lo) {
  hi = f2bf(v);
  lo = f2bf(v - bf2f(hi));
}
__device__ __forceinline__ float join2(ushort hi, ushort lo) {
  return bf2f(hi) + bf2f(lo);
}
// planar index of column c within a row (ushort offset): hi at ret, lo at ret+32
__device__ __forceinline__ int pcol(int c) { return ((c >> 5) << 6) + (c & 31); }

#define GLOAD_LDS16(gptr, ldsptr)                                                        \
  __builtin_amdgcn_global_load_lds((const __attribute__((address_space(1))) void*)(gptr), \
                                   (__attribute__((address_space(3))) void*)(ldsptr), 16, 0, 0)

// ============ 128x128 4-wave, 2 blocks/CU, 4-phase GEMM (all-planar bf16) ============
// C = (Ahi+Alo)[M,K] @ (Bhi+Blo)[N,K]^T via 3 bf16 MFMA products, fp32 accum.
// A: planar bf16 [M][2K] (per 32-elem k-block: 32 hi then 32 lo), row stride lda2.
// B: planar bf16 [N][2K], row stride ldb2.
// MODE 1: gelu(v+bias) -> planar out. MODE 2: v+bias -> planar out.
// MODE 3: fp32 partial store (deterministic split-K): outF + bz*zStrideF + row*ldcF + col.
template <int MODE>
__global__ __launch_bounds__(256, 2) void gemm_mfma(const ushort* __restrict__ A,
                                                    const ushort* __restrict__ Bw,
                                                    const float* __restrict__ bias,
                                                    float* __restrict__ outF,
                                                    ushort* __restrict__ outU,
                                                    int lda2, int ldb2, int ldc2,
                                                    int ldcF, int zStrideF, int ktiles) {
  __shared__ ushort sA[2][128 * 64];   // [buf][row][64 bf16]  128B rows (16KB/buf)
  __shared__ ushort sB[2][128 * 64];
  const int tid = threadIdx.x;
  const int w = tid >> 6;       // 0..3
  const int lane = tid & 63;
  const int wm = w >> 1;        // 0..1
  const int wn = w & 1;         // 0..1

  // bijective XCD swizzle over the whole grid (all totals % 8 == 0)
  const int gx = gridDim.x, gy = gridDim.y;
  const int flat = ((int)blockIdx.z * gy + blockIdx.y) * gx + blockIdx.x;
  const int q8 = (gx * gy * (int)gridDim.z) >> 3;
  const int swz = (flat & 7) * q8 + (flat >> 3);
  const int bx = swz % gx;
  const int by = (swz / gx) % gy;
  const int bz = swz / (gx * gy);
  const int bm = by * 128;
  const int bn = bx * 128;
  const int k0 = bz * ktiles * 64;   // ushort elements

  // staging: per 8-row/1KB DMA chunk, lane l -> row +(l>>3), phys 16B-block l&7
  // sourced from logical block (l&7)^(l>>3)  (XOR swizzle, matched on read side)
  const int srow = lane >> 3;
  const int sblk = (lane & 7) ^ srow;
  const ushort* Ab = A + (size_t)(bm + w * 32 + srow) * lda2 + k0 + sblk * 8;
  const ushort* Bb = Bw + (size_t)(bn + w * 32 + srow) * ldb2 + k0 + sblk * 8;

#define STAGE(buf, tk)                                                            \
  do {                                                                            \
    _Pragma("unroll") for (int i_ = 0; i_ < 4; ++i_) {                            \
      GLOAD_LDS16(Ab + (size_t)(tk) * 64 + (size_t)(i_ * 8) * lda2,               \
                  &sA[buf][(w * 32 + i_ * 8) * 64]);                              \
      GLOAD_LDS16(Bb + (size_t)(tk) * 64 + (size_t)(i_ * 8) * ldb2,               \
                  &sB[buf][(w * 32 + i_ * 8) * 64]);                              \
    }                                                                             \
  } while (0)

  // fragment read constants (16x16x32: row = lane&15, k = 8*(lane>>4)+0..7)
  const int fr = lane & 15;
  const int s7 = fr & 7;
  const int jb = lane >> 4;                 // 0..3
  const int hOff = (jb ^ s7) << 3;          // hi: logical blocks 0..3
  const int lOff = ((4 + jb) ^ s7) << 3;    // lo: logical blocks 4..7

  f32x4 acc[4][4] = {};
  const int NT = ktiles;

  STAGE(0, 0);
  asm volatile("s_waitcnt vmcnt(0)" ::: "memory");
  __builtin_amdgcn_s_barrier();

  for (int t = 0; t < NT; ++t) {
    const int cur = t & 1;
    if (t + 1 < NT) STAGE(cur ^ 1, t + 1);  // 8 DMAs/wave, drained at phase 4

    // phase 1 payload: all A fragments (direct short8, no unpack)
    short8 ah[4], al[4];
#pragma unroll
    for (int mi = 0; mi < 4; ++mi) {
      const ushort* baseA = &sA[cur][(wm * 64 + mi * 16 + fr) * 64];
      ah[mi] = *(const short8*)(baseA + hOff);
      al[mi] = *(const short8*)(baseA + lOff);
    }
#pragma unroll
    for (int ni = 0; ni < 4; ++ni) {  // 4 phases, one per ni
      const ushort* baseB = &sB[cur][(wn * 64 + ni * 16 + fr) * 64];
      short8 bh = *(const short8*)(baseB + hOff);
      short8 bl = *(const short8*)(baseB + lOff);
      __builtin_amdgcn_s_setprio(1);
#pragma unroll
      for (int mi = 0; mi < 4; ++mi) {
        acc[mi][ni] = __builtin_amdgcn_mfma_f32_16x16x32_bf16(ah[mi], bh, acc[mi][ni], 0, 0, 0);
        acc[mi][ni] = __builtin_amdgcn_mfma_f32_16x16x32_bf16(ah[mi], bl, acc[mi][ni], 0, 0, 0);
        acc[mi][ni] = __builtin_amdgcn_mfma_f32_16x16x32_bf16(al[mi], bh, acc[mi][ni], 0, 0, 0);
      }
      __builtin_amdgcn_s_setprio(0);
      if (ni == 3) asm volatile("s_waitcnt vmcnt(0)" ::: "memory");  // own stages landed
      __builtin_amdgcn_s_barrier();  // all waves' stages landed -> next tile readable
    }
  }
#undef STAGE

  const int erow = jb << 2;  // C/D: col=lane&15, row=(lane>>4)*4+e
#pragma unroll
  for (int ni = 0; ni < 4; ++ni) {
    const int col = bn + wn * 64 + ni * 16 + fr;
    const float bv = (MODE == 3) ? 0.f : bias[col];
    const int cb = pcol(col);
#pragma unroll
    for (int mi = 0; mi < 4; ++mi) {
#pragma unroll
      for (int e = 0; e < 4; ++e) {
        const int row = bm + wm * 64 + mi * 16 + erow + e;
        float v = acc[mi][ni][e] + bv;
        if (MODE == 1 || MODE == 2) {
          if (MODE == 1) v = gelu_tanh(v);
          ushort hi, lo;
          split2(v, hi, lo);
          outU[(size_t)row * ldc2 + cb] = hi;
          outU[(size_t)row * ldc2 + cb + 32] = lo;
        } else {
          outF[(size_t)bz * zStrideF + (size_t)row * ldcF + col] = v;
        }
      }
    }
  }
}

// W[K][N] fp32 -> planar block-interleaved bf16 [N][2K]
__global__ __launch_bounds__(256) void convert_w_t(const float* __restrict__ W,
                                                   ushort* __restrict__ WI, int K, int N) {
  __shared__ float tile[32][33];
  const int kb = blockIdx.y * 32, nb = blockIdx.x * 32;
  const int tr = threadIdx.x >> 5;
  const int tc = threadIdx.x & 31;
#pragma unroll
  for (int p = 0; p < 4; ++p) {
    int r = tr + p * 8;
    tile[r][tc] = W[(size_t)(kb + r) * N + nb + tc];
  }
  __syncthreads();
  const int kblk = kb >> 5;
#pragma unroll
  for (int p = 0; p < 4; ++p) {
    int n = tr + p * 8;
    float v = tile[tc][n];
    ushort hi, lo;
    split2(v, hi, lo);
    size_t o = (size_t)(nb + n) * (2 * K) + (size_t)kblk * 64 + tc;
    WI[o] = hi;
    WI[o + 32] = lo;
  }
}

// One block per (batch, head). qkv planar bf16 [row][4608]; writes output
// IN PLACE into the Q-slot columns (block reads all its Q/K/V to LDS first).
__global__ __launch_bounds__(256) void attn_kernel(ushort* __restrict__ qkv,
                                                   const int* __restrict__ mask) {
  __shared__ float smem[64 * 64 + 64 * 66 + 64 * 64];  // Qs | KsT | Vs ; Ps aliases
  float (*Qs)[64] = (float (*)[64])smem;
  float (*KsT)[66] = (float (*)[66])(smem + 64 * 64);
  float (*Vs)[64] = (float (*)[64])(smem + 64 * 64 + 64 * 66);
  float (*Ps)[65] = (float (*)[65])smem;

  const int bl = blockIdx.x / NH;
  const int hh = blockIdx.x % NH;
  const int tid = threadIdx.x;
  const int lane = tid & 63;
  const int w = tid >> 6;

  for (int i = 0; i < 16; ++i) {
    int idx = tid + i * 256;
    int r = idx >> 6, d = idx & 63;
    size_t rowb = (size_t)(bl * 64 + r) * 4608;
    int off = hh * 128 + pcol(d);
    Qs[r][d] = join2(qkv[rowb + off], qkv[rowb + off + 32]);
    KsT[d][r] = join2(qkv[rowb + 1536 + off], qkv[rowb + 1536 + off + 32]);
    Vs[r][d] = join2(qkv[rowb + 3072 + off], qkv[rowb + 3072 + off + 32]);
  }
  __syncthreads();

  float sc[16];
#pragma unroll
  for (int i = 0; i < 16; ++i) sc[i] = 0.f;
  for (int d = 0; d < 64; ++d) {
    float kv = KsT[d][lane];
#pragma unroll
    for (int i = 0; i < 16; ++i) sc[i] += Qs[w + 4 * i][d] * kv;
  }
  __syncthreads();
  float biask = (1.0f - (float)mask[bl * S + lane]) * -1e9f;
#pragma unroll
  for (int i = 0; i < 16; ++i) Ps[w + 4 * i][lane] = sc[i] * 0.125f + biask;
  __syncthreads();

  if (tid < 64) {
    int qr = tid;
    float mx = -1e30f;
    for (int k = 0; k < 64; ++k) mx = fmaxf(mx, Ps[qr][k]);
    float sum = 0.f;
    for (int k = 0; k < 64; ++k) {
      float e = expf(Ps[qr][k] - mx);
      Ps[qr][k] = e;
      sum += e;
    }
    float inv = 1.0f / sum;
    for (int k = 0; k < 64; ++k) Ps[qr][k] *= inv;
  }
  __syncthreads();

  float o[16];
#pragma unroll
  for (int i = 0; i < 16; ++i) o[i] = 0.f;
  for (int k = 0; k < 64; ++k) {
    float vv = Vs[k][lane];
#pragma unroll
    for (int i = 0; i < 16; ++i) o[i] += Ps[w + 4 * i][k] * vv;
  }
  const int ooff = hh * 128 + pcol(lane);
#pragma unroll
  for (int i = 0; i < 16; ++i) {
    int qr = w + 4 * i;
    size_t rowb = (size_t)(bl * 64 + qr) * 4608;
    ushort hi, lo;
    split2(o[i], hi, lo);
    qkv[rowb + ooff] = hi;
    qkv[rowb + ooff + 32] = lo;
  }
}

__global__ __launch_bounds__(256) void embed_ln_kernel(const int* __restrict__ ids,
                                                       const float* __restrict__ we,
                                                       const float* __restrict__ pe,
                                                       const float* __restrict__ te,
                                                       const float* __restrict__ g,
                                                       const float* __restrict__ bta,
                                                       ushort* __restrict__ xhl) {
  __shared__ float buf[H];
  __shared__ float red[256];
  const int row = blockIdx.x;
  const int s = row % S;
  const int tid = threadIdx.x;
  const int id = ids[row];
  float local = 0.f;
  for (int i = tid; i < H; i += 256) {
    float v = we[(size_t)id * H + i] + pe[(size_t)s * H + i] + te[i];
    buf[i] = v;
    local += v;
  }
  red[tid] = local;
  __syncthreads();
  for (int st = 128; st > 0; st >>= 1) {
    if (tid < st) red[tid] += red[tid + st];
    __syncthreads();
  }
  float mean = red[0] * (1.0f / H);
  __syncthreads();
  float ls = 0.f;
  for (int i = tid; i < H; i += 256) {
    float d = buf[i] - mean;
    ls += d * d;
  }
  red[tid] = ls;
  __syncthreads();
  for (int st = 128; st > 0; st >>= 1) {
    if (tid < st) red[tid] += red[tid + st];
    __syncthreads();
  }
  float inv = 1.0f / sqrtf(red[0] * (1.0f / H) + 1e-12f);
  for (int i = tid; i < H; i += 256) {
    float o = (buf[i] - mean) * inv * g[i] + bta[i];
    int cb = pcol(i);
    ushort hi, lo;
    split2(o, hi, lo);
    xhl[(size_t)row * (2 * H) + cb] = hi;
    xhl[(size_t)row * (2 * H) + cb + 32] = lo;
  }
}

// xhl = planar(LayerNorm(join(xhl) + p0 + p1 + bias) * g + b)   (deterministic z-sum)
__global__ __launch_bounds__(256) void add_ln_kernel(ushort* __restrict__ xhl,
                                                     const float* __restrict__ pz0,
                                                     const float* __restrict__ pz1,
                                                     int prs,
                                                     const float* __restrict__ biasv,
                                                     const float* __restrict__ g,
                                                     const float* __restrict__ bta) {
  __shared__ float buf[H];
  __shared__ float red[256];
  const size_t row = blockIdx.x;
  const int tid = threadIdx.x;
  float local = 0.f;
  for (int i = tid; i < H; i += 256) {
    int cb = pcol(i);
    float v = join2(xhl[row * (2 * H) + cb], xhl[row * (2 * H) + cb + 32]) +
              ((pz0[row * (size_t)prs + i] + pz1[row * (size_t)prs + i]) + biasv[i]);
    buf[i] = v;
    local += v;
  }
  red[tid] = local;
  __syncthreads();
  for (int st = 128; st > 0; st >>= 1) {
    if (tid < st) red[tid] += red[tid + st];
    __syncthreads();
  }
  float mean = red[0] * (1.0f / H);
  __syncthreads();
  float ls = 0.f;
  for (int i = tid; i < H; i += 256) {
    float d = buf[i] - mean;
    ls += d * d;
  }
  red[tid] = ls;
  __syncthreads();
  for (int st = 128; st > 0; st >>= 1) {
    if (tid < st) red[tid] += red[tid + st];
    __syncthreads();
  }
  float inv = 1.0f / sqrtf(red[0] * (1.0f / H) + 1e-12f);
  for (int i = tid; i < H; i += 256) {
    float o = (buf[i] - mean) * inv * g[i] + bta[i];
    int cb = pcol(i);
    ushort hi, lo;
    split2(o, hi, lo);
    xhl[row * (2 * H) + cb] = hi;
    xhl[row * (2 * H) + cb + 32] = lo;
  }
}

__global__ __launch_bounds__(256) void fc_kernel(const ushort* __restrict__ xhl,
                                                 const float* __restrict__ w,
                                                 const float* __restrict__ bias,
                                                 float* __restrict__ logits) {
  __shared__ float xs[H];
  const size_t row = blockIdx.x;
  const int tid = threadIdx.x;
  for (int i = tid; i < H; i += 256) {
    int cb = pcol(i);
    xs[i] = join2(xhl[row * (2 * H) + cb], xhl[row * (2 * H) + cb + 32]);
  }
  __syncthreads();
  const int j = tid >> 4, l = tid & 15;
  if (j < T) {
    float s = 0.f;
    for (int k = l; k < H; k += 16) s += xs[k] * w[(size_t)k * T + j];
#pragma unroll
    for (int d = 8; d > 0; d >>= 1) s += __shfl_down(s, d, 16);
    if (l == 0) logits[row * T + j] = s + bias[j];
  }
}

__global__ __launch_bounds__(64) void crf_llh_kernel(const float* __restrict__ em,
                                                     const int* __restrict__ label,
                                                     const int* __restrict__ mask,
                                                     const float* __restrict__ start,
                                                     const float* __restrict__ endw,
                                                     const float* __restrict__ trans,
                                                     float* __restrict__ llh) {
  const int b = blockIdx.x;
  const int c = threadIdx.x;
  __shared__ float alpha[T];
  __shared__ float tr[T][T];
  for (int i = c; i < T * T; i += 64) tr[i / T][i % T] = trans[i];
  if (c < T) alpha[c] = start[c] + em[(size_t)b * S * T + c];
  __syncthreads();
  for (int s = 1; s < S; ++s) {
    float a = 0.f;
    if (c < T) {
      float mx = -1e30f;
      for (int p = 0; p < T; ++p) mx = fmaxf(mx, alpha[p] + tr[p][c]);
      float sum = 0.f;
      for (int p = 0; p < T; ++p) sum += expf(alpha[p] + tr[p][c] - mx);
      a = mx + logf(sum) + em[((size_t)b * S + s) * T + c];
    }
    __syncthreads();
    if (c < T) {
      float m = (float)mask[b * S + s];
      alpha[c] = (m > 0.f) ? a : alpha[c];
    }
    __syncthreads();
  }
  if (c == 0) {
    float mx = -1e30f;
    for (int p = 0; p < T; ++p) mx = fmaxf(mx, alpha[p] + endw[p]);
    float sum = 0.f;
    for (int p = 0; p < T; ++p) sum += expf(alpha[p] + endw[p] - mx);
    float denom = mx + logf(sum);

    int t0 = label[b * S];
    float score = start[t0] + em[(size_t)b * S * T + t0];
    int prev = t0;
    for (int s = 1; s < S; ++s) {
      int tc = label[b * S + s];
      float m = (float)mask[b * S + s];
      score += (tr[prev][tc] + em[((size_t)b * S + s) * T + tc]) * m;
      prev = tc;
    }
    int msum = 0;
    for (int s = 0; s < S; ++s) msum += mask[b * S + s];
    score += endw[label[b * S + (msum - 1)]];
    llh[b] = score - denom;
  }
}

__global__ __launch_bounds__(256) void loss_kernel(const float* __restrict__ llh,
                                                   float* __restrict__ out) {
  __shared__ float red[256];
  const int tid = threadIdx.x;
  red[tid] = llh[tid];  // B == 256
  __syncthreads();
  for (int st = 128; st > 0; st >>= 1) {
    if (tid < st) red[tid] += red[tid + st];
    __syncthreads();
  }
  if (tid == 0) out[BS] = -red[0] * (1.0f / B);
}

__global__ __launch_bounds__(64) void viterbi_kernel(const float* __restrict__ em,
                                                     const int* __restrict__ mask,
                                                     const float* __restrict__ start,
                                                     const float* __restrict__ endw,
                                                     const float* __restrict__ trans,
                                                     float* __restrict__ pred) {
  const int b = blockIdx.x;
  const int c = threadIdx.x;
  __shared__ float sc[T];
  __shared__ float tr[T][T];
  __shared__ int hist[S - 1][T];
  for (int i = c; i < T * T; i += 64) tr[i / T][i % T] = trans[i];
  if (c < T) sc[c] = start[c] + em[(size_t)b * S * T + c];
  __syncthreads();
  for (int s = 1; s < S; ++s) {
    float bestv = -1e30f;
    int bestp = 0;
    if (c < T) {
      for (int p = 0; p < T; ++p) {
        float v = sc[p] + tr[p][c];
        if (v > bestv) { bestv = v; bestp = p; }
      }
      hist[s - 1][c] = bestp;
    }
    __syncthreads();
    if (c < T) {
      float m = (float)mask[b * S + s];
      sc[c] = (m > 0.f) ? (bestv + em[((size_t)b * S + s) * T + c]) : sc[c];
    }
    __syncthreads();
  }
  if (c == 0) {
    float bv = -1e30f;
    int last = 0;
    for (int p = 0; p < T; ++p) {
      float v = sc[p] + endw[p];
      if (v > bv) { bv = v; last = p; }
    }
    pred[b * S + (S - 1)] = (float)last;
    int t = last;
    for (int hs = S - 2; hs >= 0; --hs) {
      if (mask[b * S + hs + 1] > 0) t = hist[hs][t];
      pred[b * S + hs] = (float)t;
    }
  }
}

}  // namespace

extern "C" void kernel_launch(void* const* d_in, const int* in_sizes, int n_in,
                              void* d_out, int out_size, void* d_ws, size_t ws_size,
                              hipStream_t stream) {
  (void)in_sizes; (void)n_in; (void)out_size; (void)ws_size;
  const int* input_ids = (const int*)d_in[0];
  const int* attn_mask = (const int*)d_in[1];
  const int* label = (const int*)d_in[2];
  const float* word_emb = (const float*)d_in[3];
  const float* pos_emb = (const float*)d_in[4];
  const float* tok_emb = (const float*)d_in[5];
  const float* eg = (const float*)d_in[6];
  const float* ebt = (const float*)d_in[7];
  const float* Wqkv = (const float*)d_in[8];
  const float* bqkv = (const float*)d_in[9];
  const float* Wo = (const float*)d_in[10];
  const float* bo = (const float*)d_in[11];
  const float* ln1g = (const float*)d_in[12];
  const float* ln1b = (const float*)d_in[13];
  const float* W1 = (const float*)d_in[14];
  const float* b1 = (const float*)d_in[15];
  const float* W2 = (const float*)d_in[16];
  const float* b2 = (const float*)d_in[17];
  const float* ln2g = (const float*)d_in[18];
  const float* ln2b = (const float*)d_in[19];
  const float* fc_w = (const float*)d_in[20];
  const float* fc_b = (const float*)d_in[21];
  const float* crf_start = (const float*)d_in[22];
  const float* crf_end = (const float*)d_in[23];
  const float* crf_trans = (const float*)d_in[24];
  float* out = (float*)d_out;

  // ---- workspace layout (~231 MB, proven footprint) ----
  char* p = (char*)d_ws;
  ushort* xhl = (ushort*)p;    p += (size_t)BS * 2 * H * 2;      // planar residual [BS][1536]
  ushort* wQ = (ushort*)p;     p += (size_t)3 * H * 2 * H * 2;   // [2304][1536]
  ushort* wO = (ushort*)p;     p += (size_t)H * 2 * H * 2;       // [768][1536]
  ushort* wF1 = (ushort*)p;    p += (size_t)F * 2 * H * 2;       // [3072][1536]
  ushort* wF2 = (ushort*)p;    p += (size_t)H * 2 * F * 2;       // [768][6144]
  char* big = p;               p += (size_t)BS * 3 * H * 4;      // 151 MB
  float* logits = (float*)p;   p += (size_t)BS * T * 4;
  float* llh = (float*)p;      p += (size_t)B * 4;
  ushort* qkvP = (ushort*)big;             // [BS][4608] planar; attn out -> Q slot
  float* qf = (float*)big;                 // f32 row view [BS][2304]; Wo partials in K/V area
  ushort* hU = (ushort*)big;               // [RC][6144] planar (FFN phase)
  float* pf = (float*)(big + (size_t)RC * F * 4);  // [2][RC][H] fp32 FFN2 partials

  embed_ln_kernel<<<BS, 256, 0, stream>>>(input_ids, word_emb, pos_emb, tok_emb, eg, ebt, xhl);

  for (int l = 0; l < L; ++l) {
    const float* wqkv_l = Wqkv + (size_t)l * H * 3 * H;
    const float* bqkv_l = bqkv + (size_t)l * 3 * H;
    const float* wo_l = Wo + (size_t)l * H * H;
    const float* bo_l = bo + (size_t)l * H;
    const float* g1 = ln1g + (size_t)l * H;
    const float* be1 = ln1b + (size_t)l * H;
    const float* w1_l = W1 + (size_t)l * H * F;
    const float* b1_l = b1 + (size_t)l * F;
    const float* w2_l = W2 + (size_t)l * F * H;
    const float* b2_l = b2 + (size_t)l * H;
    const float* g2 = ln2g + (size_t)l * H;
    const float* be2 = ln2b + (size_t)l * H;

    convert_w_t<<<dim3(3 * H / 32, H / 32), 256, 0, stream>>>(wqkv_l, wQ, H, 3 * H);
    convert_w_t<<<dim3(H / 32, H / 32), 256, 0, stream>>>(wo_l, wO, H, H);
    convert_w_t<<<dim3(F / 32, H / 32), 256, 0, stream>>>(w1_l, wF1, H, F);
    convert_w_t<<<dim3(H / 32, F / 32), 256, 0, stream>>>(w2_l, wF2, F, H);

    // ---- attention block ----
    // QKV: [BS,H] @ [H,3H] -> qkvP planar.  grid 18x128 = 2304 (9/CU)
    gemm_mfma<2><<<dim3(3 * H / 128, BS / 128, 1), 256, 0, stream>>>(
        xhl, wQ, bqkv_l, nullptr, qkvP, 2 * H, 2 * H, 2 * 3 * H, 0, 0, H / 32);
    attn_kernel<<<B * NH, 256, 0, stream>>>(qkvP, attn_mask);
    // Wo: [BS,H(Q-slot)] @ [H,H] -> fp32 partials into dead K/V area (z=2, deterministic)
    gemm_mfma<3><<<dim3(H / 128, BS / 128, 2), 256, 0, stream>>>(
        qkvP, wO, nullptr, qf + H, nullptr, 2 * 3 * H, 2 * H, 0, 3 * H, H, H / 64);
    add_ln_kernel<<<BS, 256, 0, stream>>>(xhl, qf + H, qf + 2 * H, 3 * H, bo_l, g1, be1);

    // ---- FFN block (chunked) ----
    for (int ch = 0; ch < NCH; ++ch) {
      // FFN1: [RC,H] @ [H,F] -> hU (gelu, planar).  grid 24x64 = 1536 (6/CU)
      gemm_mfma<1><<<dim3(F / 128, RC / 128, 1), 256, 0, stream>>>(
          xhl + (size_t)ch * RC * 2 * H, wF1, b1_l, nullptr, hU, 2 * H, 2 * H, 2 * F,
          0, 0, H / 32);
      // FFN2: [RC,F] @ [F,H] -> fp32 partials pf (z=2).  grid 6x64x2 = 768 (3/CU)
      gemm_mfma<3><<<dim3(H / 128, RC / 128, 2), 256, 0, stream>>>(
          hU, wF2, nullptr, pf, nullptr, 2 * F, 2 * F, 0, H, RC * H, F / 64);
      add_ln_kernel<<<RC, 256, 0, stream>>>(xhl + (size_t)ch * RC * 2 * H, pf,
                                            pf + (size_t)RC * H, H, b2_l, g2, be2);
    }
  }

  fc_kernel<<<BS, 256, 0, stream>>>(xhl, fc_w, fc_b, logits);
  crf_llh_kernel<<<B, 64, 0, stream>>>(logits, label, attn_mask, crf_start, crf_end, crf_trans, llh);
  loss_kernel<<<1, 256, 0, stream>>>(llh, out);
  viterbi_kernel<<<B, 64, 0, stream>>>(logits, attn_mask, crf_start, crf_end, crf_trans, out);
}